// Round 8
// baseline (826.998 us; speedup 1.0000x reference)
//
#include <hip/hip_runtime.h>
#include <hip/hip_fp16.h>

#define BLK 256
#define NBSHIFT 9     // 512 nodes per bucket
#define MAXNB 200     // supports n <= 102400
#define GPART 512     // partition blocks

typedef _Float16 half4v __attribute__((ext_vector_type(4)));
typedef _Float16 half8v __attribute__((ext_vector_type(8)));
typedef float    f32x4v __attribute__((ext_vector_type(4)));

__device__ __forceinline__ float4 ld4(const float* p) { return *(const float4*)p; }

// ================= CSR build: atomic-free radix partition by col>>NBSHIFT =================
__global__ __launch_bounds__(BLK) void p1_hist_k(const int* __restrict__ cols, int* __restrict__ hist,
                                                 int E, int nb) {
    __shared__ int h[MAXNB];
    const int tid = threadIdx.x, g = blockIdx.x;
    for (int b = tid; b < nb; b += BLK) h[b] = 0;
    __syncthreads();
    const int chunk = (E + GPART - 1) / GPART;
    const int start = g * chunk, end = min(E, start + chunk);
    for (int e = start + tid; e < end; e += BLK) atomicAdd(&h[cols[e] >> NBSHIFT], 1);
    __syncthreads();
    for (int b = tid; b < nb; b += BLK) hist[b * GPART + g] = h[b];
}
__global__ __launch_bounds__(256) void p2a_k(const int* __restrict__ hist, int* __restrict__ bstart,
                                             int nb, int E) {
    __shared__ int s[256];
    const int t = threadIdx.x;
    int tot = 0;
    if (t < nb) {
        const int* hp = &hist[t * GPART];
        for (int g = 0; g < GPART; g++) tot += hp[g];
    }
    s[t] = tot;
    __syncthreads();
    for (int o = 1; o < 256; o <<= 1) {
        int v = s[t] + ((t >= o) ? s[t - o] : 0);
        __syncthreads();
        s[t] = v;
        __syncthreads();
    }
    if (t < nb) bstart[t] = s[t] - tot;
    if (t == 0) bstart[nb] = E;
}
__global__ __launch_bounds__(256) void p2b_k(int* __restrict__ hist, const int* __restrict__ bstart) {
    __shared__ int s[GPART];
    const int b = blockIdx.x, t = threadIdx.x;
    const int v0 = hist[b * GPART + t], v1 = hist[b * GPART + 256 + t];
    s[t] = v0; s[256 + t] = v1;
    __syncthreads();
    for (int o = 1; o < GPART; o <<= 1) {
        const int a0 = s[t] + ((t >= o) ? s[t - o] : 0);
        const int a1 = s[256 + t] + ((256 + t >= o) ? s[256 + t - o] : 0);
        __syncthreads();
        s[t] = a0; s[256 + t] = a1;
        __syncthreads();
    }
    const int base = bstart[b];
    hist[b * GPART + t] = base + s[t] - v0;
    hist[b * GPART + 256 + t] = base + s[256 + t] - v1;
}
__global__ __launch_bounds__(BLK) void p3_part_k(const int* __restrict__ rows, const int* __restrict__ cols,
                                                 const int* __restrict__ hist, int2* __restrict__ pairs,
                                                 int E, int nb) {
    __shared__ int tail[MAXNB];
    const int tid = threadIdx.x, g = blockIdx.x;
    for (int b = tid; b < nb; b += BLK) tail[b] = hist[b * GPART + g];
    __syncthreads();
    const int chunk = (E + GPART - 1) / GPART;
    const int start = g * chunk, end = min(E, start + chunk);
    for (int e = start + tid; e < end; e += BLK) {
        const int r = rows[e], c = cols[e];
        const int pos = atomicAdd(&tail[c >> NBSHIFT], 1);
        pairs[pos] = make_int2(r, c);
    }
}
__global__ __launch_bounds__(BLK) void p4_fill_k(const int2* __restrict__ pairs, const int* __restrict__ bstart,
                                                 int* __restrict__ P, float* __restrict__ dinv,
                                                 int* __restrict__ srow, int n) {
    __shared__ int dh[1 << NBSHIFT];
    __shared__ int tl[1 << NBSHIFT];
    const int b = blockIdx.x, t = threadIdx.x;
    const int base = b << NBSHIFT;
    const int nnod = min(1 << NBSHIFT, n - base);
    const int lo = bstart[b], hi = bstart[b + 1];
    dh[t] = 0; dh[256 + t] = 0;
    __syncthreads();
    for (int e = lo + t; e < hi; e += BLK) atomicAdd(&dh[pairs[e].y - base], 1);
    __syncthreads();
    const int v0 = dh[t], v1 = dh[256 + t];
    tl[t] = v0; tl[256 + t] = v1;
    __syncthreads();
    for (int o = 1; o < (1 << NBSHIFT); o <<= 1) {
        const int a0 = tl[t] + ((t >= o) ? tl[t - o] : 0);
        const int a1 = tl[256 + t] + ((256 + t >= o) ? tl[256 + t - o] : 0);
        __syncthreads();
        tl[t] = a0; tl[256 + t] = a1;
        __syncthreads();
    }
    const int s0 = lo + tl[t] - v0;          // exclusive start of node base+t
    const int s1 = lo + tl[256 + t] - v1;
    __syncthreads();
    tl[t] = s0; tl[256 + t] = s1;
    if (t < nnod)       { P[base + t] = s0;       dinv[base + t] = rsqrtf((float)v0 + 1.0f); }
    if (256 + t < nnod) { P[base + 256 + t] = s1; dinv[base + 256 + t] = rsqrtf((float)v1 + 1.0f); }
    __syncthreads();
    for (int e = lo + t; e < hi; e += BLK) {
        const int2 pr = pairs[e];
        const int pos = atomicAdd(&tl[pr.y - base], 1);
        srow[pos] = pr.x;
    }
}

// ================= fp16-input gather over a 16-feature slice table =================
// Table Ts: [n][16] halves (one slice, 3.2MB -> L2-resident per XCD).
// out[i][qout + q .. +8] = dinv[i] * ( Ts[i] + sum_e Ts[srow[e]] )   (row-major out, stride WDO)
__device__ __forceinline__ void addh(float2 A[4], const __half* p) {
    const float4 raw = ld4((const float*)p);
    const __half2* h = (const __half2*)&raw;
    const float2 f0 = __half22float2(h[0]);
    const float2 f1 = __half22float2(h[1]);
    const float2 f2 = __half22float2(h[2]);
    const float2 f3 = __half22float2(h[3]);
    A[0].x += f0.x; A[0].y += f0.y;
    A[1].x += f1.x; A[1].y += f1.y;
    A[2].x += f2.x; A[2].y += f2.y;
    A[3].x += f3.x; A[3].y += f3.y;
}

template<bool OUTH>
__global__ __launch_bounds__(BLK) void gslice_k(const __half* __restrict__ Ts, const int* __restrict__ P,
                                                const int* __restrict__ srow, const float* __restrict__ dinv,
                                                void* __restrict__ outv, int n, int E, int qout, int WDO) {
    const long gid = (long)blockIdx.x * BLK + threadIdx.x;
    const int i = (int)(gid >> 1);
    if (i >= n) return;
    const int q = (int)(gid & 1) * 8;
    const int start = P[i];
    const int end = (i + 1 < n) ? P[i + 1] : E;
    const float d = dinv[i];
    const __half* __restrict__ Tq = Ts + q;
    float2 A0[4], A1[4], A2[4], A3[4];
    {   // self-loop
        const float4 raw = ld4((const float*)(Tq + (long)i * 16));
        const __half2* h = (const __half2*)&raw;
        A0[0] = __half22float2(h[0]); A0[1] = __half22float2(h[1]);
        A0[2] = __half22float2(h[2]); A0[3] = __half22float2(h[3]);
    }
#pragma unroll
    for (int k = 0; k < 4; k++) {
        A1[k] = make_float2(0.f, 0.f); A2[k] = make_float2(0.f, 0.f); A3[k] = make_float2(0.f, 0.f);
    }
    int e = start;
    const int ea = min(end, (start + 3) & ~3);   // align srow to int4
    for (; e < ea; e++) addh(A0, Tq + (long)srow[e] * 16);
    for (; e + 8 <= end; e += 8) {
        const int4 j0 = *(const int4*)&srow[e];
        const int4 j1 = *(const int4*)&srow[e + 4];
        addh(A0, Tq + (long)j0.x * 16); addh(A1, Tq + (long)j0.y * 16);
        addh(A2, Tq + (long)j0.z * 16); addh(A3, Tq + (long)j0.w * 16);
        addh(A0, Tq + (long)j1.x * 16); addh(A1, Tq + (long)j1.y * 16);
        addh(A2, Tq + (long)j1.z * 16); addh(A3, Tq + (long)j1.w * 16);
    }
    if (e + 4 <= end) {
        const int4 j0 = *(const int4*)&srow[e];
        addh(A0, Tq + (long)j0.x * 16); addh(A1, Tq + (long)j0.y * 16);
        addh(A2, Tq + (long)j0.z * 16); addh(A3, Tq + (long)j0.w * 16);
        e += 4;
    }
    for (; e < end; e++) addh(A0, Tq + (long)srow[e] * 16);
#pragma unroll
    for (int k = 0; k < 4; k++) {
        A0[k].x += A1[k].x + A2[k].x + A3[k].x;
        A0[k].y += A1[k].y + A2[k].y + A3[k].y;
    }
    float v[8];
    v[0] = d * A0[0].x; v[1] = d * A0[0].y; v[2] = d * A0[1].x; v[3] = d * A0[1].y;
    v[4] = d * A0[2].x; v[5] = d * A0[2].y; v[6] = d * A0[3].x; v[7] = d * A0[3].y;
    if (OUTH) {
        const __half2 h0 = __floats2half2_rn(v[0], v[1]);
        const __half2 h1 = __floats2half2_rn(v[2], v[3]);
        const __half2 h2 = __floats2half2_rn(v[4], v[5]);
        const __half2 h3 = __floats2half2_rn(v[6], v[7]);
        uint4 u;
        u.x = *(const unsigned int*)&h0; u.y = *(const unsigned int*)&h1;
        u.z = *(const unsigned int*)&h2; u.w = *(const unsigned int*)&h3;
        *(uint4*)&((__half*)outv)[(long)i * WDO + qout + q] = u;
    } else {
        float* o = (float*)outv;
        float4 v0, v1;
        v0.x = v[0]; v0.y = v[1]; v0.z = v[2]; v0.w = v[3];
        v1.x = v[4]; v1.y = v[5]; v1.z = v[6]; v1.w = v[7];
        *(float4*)&o[(long)i * WDO + qout + q] = v0;
        *(float4*)&o[(long)i * WDO + qout + q + 4] = v1;
    }
}

// ================= fp16 gather, row-major table (kept for WD=16 tables, already L2-fit) ======
template<int WD, bool PRE, bool OUTH>
__global__ __launch_bounds__(BLK) void gatherh_k(const __half* __restrict__ Tp, const int* __restrict__ P,
                                                 const int* __restrict__ srow, const float* __restrict__ dinv,
                                                 const float* __restrict__ bin, void* __restrict__ outv,
                                                 int n, int E) {
    constexpr int LPN = WD / 8;   // lanes per node
    const long gid = (long)blockIdx.x * BLK + threadIdx.x;
    const int i = (int)(gid / LPN);
    if (i >= n) return;
    const int q = (int)(gid % LPN) * 8;
    const int start = P[i];
    const int end = (i + 1 < n) ? P[i + 1] : E;
    const float d = dinv[i];
    const __half* __restrict__ Tq = Tp + q;
    float2 A0[4], A1[4], A2[4], A3[4];
    {   // self-loop
        const float4 raw = ld4((const float*)(Tq + (long)i * WD));
        const __half2* h = (const __half2*)&raw;
        A0[0] = __half22float2(h[0]); A0[1] = __half22float2(h[1]);
        A0[2] = __half22float2(h[2]); A0[3] = __half22float2(h[3]);
    }
#pragma unroll
    for (int k = 0; k < 4; k++) {
        A1[k] = make_float2(0.f, 0.f); A2[k] = make_float2(0.f, 0.f); A3[k] = make_float2(0.f, 0.f);
    }
    int e = start;
    const int ea = min(end, (start + 3) & ~3);   // align srow to int4
    for (; e < ea; e++) addh(A0, Tq + (long)srow[e] * WD);
    for (; e + 8 <= end; e += 8) {
        const int4 j0 = *(const int4*)&srow[e];
        const int4 j1 = *(const int4*)&srow[e + 4];
        addh(A0, Tq + (long)j0.x * WD); addh(A1, Tq + (long)j0.y * WD);
        addh(A2, Tq + (long)j0.z * WD); addh(A3, Tq + (long)j0.w * WD);
        addh(A0, Tq + (long)j1.x * WD); addh(A1, Tq + (long)j1.y * WD);
        addh(A2, Tq + (long)j1.z * WD); addh(A3, Tq + (long)j1.w * WD);
    }
    if (e + 4 <= end) {
        const int4 j0 = *(const int4*)&srow[e];
        addh(A0, Tq + (long)j0.x * WD); addh(A1, Tq + (long)j0.y * WD);
        addh(A2, Tq + (long)j0.z * WD); addh(A3, Tq + (long)j0.w * WD);
        e += 4;
    }
    for (; e < end; e++) addh(A0, Tq + (long)srow[e] * WD);
#pragma unroll
    for (int k = 0; k < 4; k++) {
        A0[k].x += A1[k].x + A2[k].x + A3[k].x;
        A0[k].y += A1[k].y + A2[k].y + A3[k].y;
    }
    float v[8];
    v[0] = d * A0[0].x; v[1] = d * A0[0].y; v[2] = d * A0[1].x; v[3] = d * A0[1].y;
    v[4] = d * A0[2].x; v[5] = d * A0[2].y; v[6] = d * A0[3].x; v[7] = d * A0[3].y;
    if (PRE) {
        const float4 b0 = ld4(&bin[q]);
        const float4 b1 = ld4(&bin[q + 4]);
        v[0] = fmaxf(v[0] + b0.x, 0.f) * d; v[1] = fmaxf(v[1] + b0.y, 0.f) * d;
        v[2] = fmaxf(v[2] + b0.z, 0.f) * d; v[3] = fmaxf(v[3] + b0.w, 0.f) * d;
        v[4] = fmaxf(v[4] + b1.x, 0.f) * d; v[5] = fmaxf(v[5] + b1.y, 0.f) * d;
        v[6] = fmaxf(v[6] + b1.z, 0.f) * d; v[7] = fmaxf(v[7] + b1.w, 0.f) * d;
    }
    if (OUTH) {
        const __half2 h0 = __floats2half2_rn(v[0], v[1]);
        const __half2 h1 = __floats2half2_rn(v[2], v[3]);
        const __half2 h2 = __floats2half2_rn(v[4], v[5]);
        const __half2 h3 = __floats2half2_rn(v[6], v[7]);
        uint4 u;
        u.x = *(const unsigned int*)&h0; u.y = *(const unsigned int*)&h1;
        u.z = *(const unsigned int*)&h2; u.w = *(const unsigned int*)&h3;
        *(uint4*)((__half*)outv + (long)i * WD + q) = u;
    } else {
        float* out = (float*)outv;
        float4 v0, v1;
        v0.x = v[0]; v0.y = v[1]; v0.z = v[2]; v0.w = v[3];
        v1.x = v[4]; v1.y = v[5]; v1.z = v[6]; v1.w = v[7];
        *(float4*)&out[(long)i * WD + q] = v0;
        *(float4*)&out[(long)i * WD + q + 4] = v1;
    }
}

// ================= fp32 LDS-tiled GEMM (small layers L2-L5) =================
// SLICEH: fp16 output written slice-major [FO/16][n][16] (feeds gslice_k passes).
template<int FI, int FO, bool INB, bool OUTB, bool OUTRELU, bool OSC, bool OUTH, bool SLICEH>
__global__ __launch_bounds__(BLK) void gemm_k(const float* __restrict__ H, const float* __restrict__ Wm,
                                              const float* __restrict__ bin, const float* __restrict__ bout,
                                              const float* __restrict__ dinv, float* __restrict__ out, int n) {
    constexpr int COLT = FO / 4;
    constexpr int RTH  = BLK / COLT;
    constexpr int RPT  = (FO >= 64) ? 8 : 4;
    constexpr int ROWS = RTH * RPT;
    constexpr int KC   = (FI > 64) ? 64 : FI;
    constexpr int NKB  = FI / KC;

    __shared__ float Wl[KC * FO];
    __shared__ float Hl[ROWS * (KC + 1)];

    const int tid    = threadIdx.x;
    const int colIdx = tid % COLT;
    const int rowIdx = tid / COLT;
    const long rowBase = (long)blockIdx.x * ROWS;

    float4 acc[RPT];
#pragma unroll
    for (int i = 0; i < RPT; i++) acc[i] = make_float4(0.f, 0.f, 0.f, 0.f);

    for (int kb = 0; kb < NKB; kb++) {
        if (kb) __syncthreads();
        for (int f = tid * 4; f < KC * FO; f += BLK * 4) {
            const int kr = f / FO, c = f % FO;
            *(float4*)&Wl[kr * FO + c] = ld4(&Wm[(kb * KC + kr) * FO + c]);
        }
        for (int f = tid * 4; f < ROWS * KC; f += BLK * 4) {
            const int rr = f / KC, kk = f % KC;
            const long r = rowBase + rr;
            float4 v = make_float4(0.f, 0.f, 0.f, 0.f);
            if (r < n) v = ld4(&H[r * FI + kb * KC + kk]);
            if (INB) {
                float4 b4 = ld4(&bin[kb * KC + kk]);
                v.x = fmaxf(v.x + b4.x, 0.f); v.y = fmaxf(v.y + b4.y, 0.f);
                v.z = fmaxf(v.z + b4.z, 0.f); v.w = fmaxf(v.w + b4.w, 0.f);
            }
            float* dst = &Hl[rr * (KC + 1) + kk];
            dst[0] = v.x; dst[1] = v.y; dst[2] = v.z; dst[3] = v.w;
        }
        __syncthreads();
#pragma unroll 8
        for (int k = 0; k < KC; k++) {
            const float4 w4 = *(const float4*)&Wl[k * FO + 4 * colIdx];
#pragma unroll
            for (int i = 0; i < RPT; i++) {
                const float hv = Hl[(rowIdx * RPT + i) * (KC + 1) + k];
                acc[i].x = fmaf(hv, w4.x, acc[i].x);
                acc[i].y = fmaf(hv, w4.y, acc[i].y);
                acc[i].z = fmaf(hv, w4.z, acc[i].z);
                acc[i].w = fmaf(hv, w4.w, acc[i].w);
            }
        }
    }

    float4 bo = make_float4(0.f, 0.f, 0.f, 0.f);
    if (OUTB) bo = ld4(&bout[4 * colIdx]);
#pragma unroll
    for (int i = 0; i < RPT; i++) {
        const long r = rowBase + rowIdx * RPT + i;
        if (r < n) {
            float4 v = acc[i];
            if (OUTB) { v.x += bo.x; v.y += bo.y; v.z += bo.z; v.w += bo.w; }
            if (OUTRELU) {
                v.x = fmaxf(v.x, 0.f); v.y = fmaxf(v.y, 0.f);
                v.z = fmaxf(v.z, 0.f); v.w = fmaxf(v.w, 0.f);
            }
            if (OSC) {
                const float d = dinv[r];
                v.x *= d; v.y *= d; v.z *= d; v.w *= d;
            }
            if (OUTH) {
                const __half2 h01 = __floats2half2_rn(v.x, v.y);
                const __half2 h23 = __floats2half2_rn(v.z, v.w);
                uint2 u;
                u.x = *(const unsigned int*)&h01;
                u.y = *(const unsigned int*)&h23;
                long base;
                if (SLICEH) base = (long)(colIdx >> 2) * ((long)n * 16) + r * 16 + ((4 * colIdx) & 15);
                else        base = r * FO + 4 * colIdx;
                *(uint2*)((__half*)out + base) = u;
            } else {
                *(float4*)&out[r * FO + 4 * colIdx] = v;
            }
        }
    }
}

// ================= MFMA fp16 GEMM for the big layers (L1, L6, final) =================
// SLICE: fp16 output written slice-major [FO/16][n][16].
template<int K, int FO, bool AH, bool OUTB, bool OUTRELU, bool OSC, bool OUTH, bool SLICE>
__global__ __launch_bounds__(BLK) void mgemm_k(const void* __restrict__ Hv, const float* __restrict__ Wm,
                                               const float* __restrict__ bout, const float* __restrict__ dinv,
                                               void* __restrict__ outv, int n) {
    constexpr int BM = 128;            // rows per block (4 waves x 32 rows)
    constexpr int KP = K + 8;          // padded row stride (halves)
    constexpr int NT = FO / 16;        // 16-col tiles
    __shared__ _Float16 Al[BM * KP];
    __shared__ _Float16 Bl[FO * KP];

    const int tid = threadIdx.x;
    const long rowBase = (long)blockIdx.x * BM;

    // ---- stage W ----
    for (int f = tid * 4; f < K * FO; f += BLK * 4) {
        const int nn = f / K, k0 = f % K;          // k0 % 4 == 0
        const int blk = k0 & ~31, g = (k0 >> 2) & 3, h = (k0 >> 4) & 1;
        half4v w4;
#pragma unroll
        for (int c = 0; c < 4; c++) w4[c] = (_Float16)Wm[(k0 + c) * FO + nn];
        *(half4v*)&Bl[nn * KP + blk + 8 * g + 4 * h] = w4;
    }
    // ---- stage A ----
    if (AH) {
        const __half* Hp = (const __half*)Hv;
        for (int f = tid * 8; f < BM * K; f += BLK * 8) {
            const int rr = f / K, k0 = f % K;      // k0 % 8 == 0
            const long r = rowBase + rr;
            uint4 u = make_uint4(0u, 0u, 0u, 0u);
            if (r < n) u = *(const uint4*)&Hp[r * K + k0];
            const int blk = k0 & ~31, g0 = (k0 >> 2) & 3, h = (k0 >> 4) & 1;
            *(uint2*)&Al[rr * KP + blk + 8 * g0 + 4 * h] = make_uint2(u.x, u.y);
            *(uint2*)&Al[rr * KP + blk + 8 * (g0 + 1) + 4 * h] = make_uint2(u.z, u.w);
        }
    } else {
        const float* Hp = (const float*)Hv;
        for (int f = tid * 4; f < BM * K; f += BLK * 4) {
            const int rr = f / K, k0 = f % K;      // k0 % 4 == 0
            const long r = rowBase + rr;
            float4 v = make_float4(0.f, 0.f, 0.f, 0.f);
            if (r < n) v = ld4(&Hp[r * K + k0]);
            const int blk = k0 & ~31, g = (k0 >> 2) & 3, h = (k0 >> 4) & 1;
            half4v a4;
            a4[0] = (_Float16)v.x; a4[1] = (_Float16)v.y; a4[2] = (_Float16)v.z; a4[3] = (_Float16)v.w;
            *(half4v*)&Al[rr * KP + blk + 8 * g + 4 * h] = a4;
        }
    }
    __syncthreads();

    // ---- MFMA main loop ----
    const int wv = tid >> 6;
    const int lane = tid & 63;
    const int lr = lane & 15;
    const int lg = lane >> 4;
    const int wrow = wv * 32;

    const f32x4v vzero = {0.f, 0.f, 0.f, 0.f};
    f32x4v acc[2][NT];
#pragma unroll
    for (int a = 0; a < 2; a++)
#pragma unroll
        for (int t = 0; t < NT; t++) acc[a][t] = vzero;

#pragma unroll
    for (int ks = 0; ks < K / 32; ks++) {
        const int ko = ks * 32 + 8 * lg;
        const half8v a0 = *(const half8v*)&Al[(wrow + lr) * KP + ko];
        const half8v a1 = *(const half8v*)&Al[(wrow + 16 + lr) * KP + ko];
#pragma unroll
        for (int nt = 0; nt < NT; nt++) {
            const half8v b = *(const half8v*)&Bl[(nt * 16 + lr) * KP + ko];
            acc[0][nt] = __builtin_amdgcn_mfma_f32_16x16x32_f16(a0, b, acc[0][nt], 0, 0, 0);
            acc[1][nt] = __builtin_amdgcn_mfma_f32_16x16x32_f16(a1, b, acc[1][nt], 0, 0, 0);
        }
    }

    // ---- epilogue ----
    float bo[NT];
    if (OUTB) {
#pragma unroll
        for (int nt = 0; nt < NT; nt++) bo[nt] = bout[nt * 16 + lr];
    }
#pragma unroll
    for (int rt = 0; rt < 2; rt++) {
#pragma unroll
        for (int r = 0; r < 4; r++) {
            const long row = rowBase + wrow + rt * 16 + lg * 4 + r;
            if (row < n) {
                const float d = OSC ? dinv[row] : 1.0f;
#pragma unroll
                for (int nt = 0; nt < NT; nt++) {
                    float v = acc[rt][nt][r];
                    if (OUTB) v += bo[nt];
                    if (OUTRELU) v = fmaxf(v, 0.f);
                    if (OSC) v *= d;
                    if (OUTH) {
                        if (SLICE) ((__half*)outv)[(long)nt * ((long)n * 16) + row * 16 + lr] = __float2half_rn(v);
                        else       ((__half*)outv)[row * FO + nt * 16 + lr] = __float2half_rn(v);
                    } else {
                        ((float*)outv)[row * FO + nt * 16 + lr] = v;
                    }
                }
            }
        }
    }
}

extern "C" void kernel_launch(void* const* d_in, const int* in_sizes, int n_in,
                              void* d_out, int out_size, void* d_ws, size_t ws_size,
                              hipStream_t stream)
{
    const float* x  = (const float*)d_in[0];
    const int*   ei = (const int*)d_in[1];
    const float* W1 = (const float*)d_in[3];  const float* b1 = (const float*)d_in[4];
    const float* W2 = (const float*)d_in[5];  const float* b2 = (const float*)d_in[6];
    const float* W3 = (const float*)d_in[7];  const float* b3 = (const float*)d_in[8];
    const float* W4 = (const float*)d_in[9];  const float* b4 = (const float*)d_in[10];
    const float* W5 = (const float*)d_in[11]; const float* b5 = (const float*)d_in[12];
    const float* W6 = (const float*)d_in[13]; const float* b6 = (const float*)d_in[14];
    const float* Wf = (const float*)d_in[15]; const float* bf = (const float*)d_in[16];

    const int n = in_sizes[0] / 128;
    const int E = in_sizes[1] / 2;
    const int* rows = ei;       // source j
    const int* cols = ei + E;   // target i

    // workspace layout — total (n + E + n + 128n + 128n)*4 = 116,000,000 B (proven safe).
    int*   P    = (int*)d_ws;                        // n ints
    int*   srow = P + n;                             // E ints (16B-aligned for n%4==0)
    float* dinv = (float*)(srow + E);                // n floats
    float* bufA = dinv + n;                          // n*128 floats
    float* bufB = bufA + (size_t)n * 128;            // n*128 floats
    // pre-layer aliases (dead before first use of bufA/bufB by the layer pipeline):
    int2*  pairs = (int2*)bufA;                      // E int2 = 25.6MB <= 51.2MB
    int*   hist  = (int*)bufB;                       // MAXNB*GPART ints = 409KB
    int*   bstart= hist + MAXNB * GPART;             // nb+1 ints

    auto cdiv = [](long a, long b) { return (unsigned)((a + b - 1) / b); };
    const int nb = (n + (1 << NBSHIFT) - 1) >> NBSHIFT;
    const size_t SL = (size_t)n * 16;                // halves per 16-feature slice

    // --- CSR build (atomic-free radix partition) ---
    p1_hist_k<<<GPART, BLK, 0, stream>>>(cols, hist, E, nb);
    p2a_k<<<1, 256, 0, stream>>>(hist, bstart, nb, E);
    p2b_k<<<nb, 256, 0, stream>>>(hist, bstart);
    p3_part_k<<<GPART, BLK, 0, stream>>>(rows, cols, hist, pairs, E, nb);
    p4_fill_k<<<nb, BLK, 0, stream>>>(pairs, bstart, P, dinv, srow, n);

    const unsigned GG = cdiv((long)n * 2, BLK);      // grid for one gslice pass

    // --- layers (gather tables fp16 slice-major; big GEMMs fp16-MFMA, fp32 accumulate) ---
    // L1 (MFMA): t1' = (x@W1)*dinv [fp16, 4 slices] ; a1 = 4x gslice -> bufB fp32 [n][64]
    mgemm_k<128, 64, false, false, false, true, true, true><<<cdiv(n, 128), BLK, 0, stream>>>(x, W1, nullptr, dinv, bufA, n);
    for (int s = 0; s < 4; s++)
        gslice_k<false><<<GG, BLK, 0, stream>>>((const __half*)bufA + s * SL, P, srow, dinv, bufB, n, E, s * 16, 64);

    // L2: t2' = (relu(a1+b1)@W2)*dinv [fp16, 2 slices] ; a2 = 2x gslice -> bufB fp32 [n][32]
    gemm_k<64, 32, true, false, false, true, true, true><<<cdiv(n, 128), BLK, 0, stream>>>(bufB, W2, b1, nullptr, dinv, bufA, n);
    for (int s = 0; s < 2; s++)
        gslice_k<false><<<GG, BLK, 0, stream>>>((const __half*)bufA + s * SL, P, srow, dinv, bufB, n, E, s * 16, 32);

    // L3: t3' = (relu(a2+b2)@W3)*dinv [fp16 WD16 row-major] ; gather w/ fused epilogue -> t4' [fp16 WD16]
    gemm_k<32, 16, true, false, false, true, true, false><<<cdiv(n, 256), BLK, 0, stream>>>(bufB, W3, b2, nullptr, dinv, bufA, n);
    gatherh_k<16, true, true><<<cdiv((long)n * 2, BLK), BLK, 0, stream>>>((const __half*)bufA, P, srow, dinv, b3, bufB, n, E);

    // L4: a4 = gather_h(t4') -> bufA fp32 [n][16] ; h4' = relu(a4@W4+b4)*dinv [fp16, 2 slices]
    gatherh_k<16, false, false><<<cdiv((long)n * 2, BLK), BLK, 0, stream>>>((const __half*)bufB, P, srow, dinv, nullptr, bufA, n, E);
    gemm_k<16, 32, false, true, true, true, true, true><<<cdiv(n, 128), BLK, 0, stream>>>(bufA, W4, nullptr, b4, dinv, bufB, n);

    // L5: a5 = 2x gslice(h4') -> bufA fp32 [n][32] ; h5' = relu(a5@W5+b5)*dinv [fp16, 4 slices]
    for (int s = 0; s < 2; s++)
        gslice_k<false><<<GG, BLK, 0, stream>>>((const __half*)bufB + s * SL, P, srow, dinv, bufA, n, E, s * 16, 32);
    gemm_k<32, 64, false, true, true, true, true, true><<<cdiv(n, 128), BLK, 0, stream>>>(bufA, W5, nullptr, b5, dinv, bufB, n);

    // L6: a6 = 4x gslice(h5') -> bufA fp16 row-major [n][64] ; (MFMA) h6 = relu(a6@W6+b6) [fp16 row-major]
    for (int s = 0; s < 4; s++)
        gslice_k<true><<<GG, BLK, 0, stream>>>((const __half*)bufB + s * SL, P, srow, dinv, bufA, n, E, s * 16, 64);
    mgemm_k<64, 128, true, true, true, false, true, false><<<cdiv(n, 128), BLK, 0, stream>>>(bufA, W6, b6, nullptr, bufB, n);

    // final (MFMA): out = h6 @ Wf + bf  [fp32 out]
    mgemm_k<128, 128, true, true, false, false, false, false><<<cdiv(n, 128), BLK, 0, stream>>>(bufB, Wf, bf, nullptr, d_out, n);
}

// Round 9
// 611.056 us; speedup vs baseline: 1.3534x; 1.3534x over previous
//
#include <hip/hip_runtime.h>
#include <hip/hip_fp16.h>

#define BLK 256
#define NBSHIFT 9     // 512 nodes per bucket
#define MAXNB 200     // supports n <= 102400
#define GPART 512     // partition blocks

typedef _Float16 half4v __attribute__((ext_vector_type(4)));
typedef _Float16 half8v __attribute__((ext_vector_type(8)));
typedef float    f32x4v __attribute__((ext_vector_type(4)));

__device__ __forceinline__ float4 ld4(const float* p) { return *(const float4*)p; }

// ================= CSR build: atomic-free radix partition by col>>NBSHIFT =================
__global__ __launch_bounds__(BLK) void p1_hist_k(const int* __restrict__ cols, int* __restrict__ hist,
                                                 int E, int nb) {
    __shared__ int h[MAXNB];
    const int tid = threadIdx.x, g = blockIdx.x;
    for (int b = tid; b < nb; b += BLK) h[b] = 0;
    __syncthreads();
    const int chunk = (E + GPART - 1) / GPART;
    const int start = g * chunk, end = min(E, start + chunk);
    for (int e = start + tid; e < end; e += BLK) atomicAdd(&h[cols[e] >> NBSHIFT], 1);
    __syncthreads();
    for (int b = tid; b < nb; b += BLK) hist[b * GPART + g] = h[b];
}
__global__ __launch_bounds__(256) void p2a_k(const int* __restrict__ hist, int* __restrict__ bstart,
                                             int nb, int E) {
    __shared__ int s[256];
    const int t = threadIdx.x;
    int tot = 0;
    if (t < nb) {
        const int* hp = &hist[t * GPART];
        for (int g = 0; g < GPART; g++) tot += hp[g];
    }
    s[t] = tot;
    __syncthreads();
    for (int o = 1; o < 256; o <<= 1) {
        int v = s[t] + ((t >= o) ? s[t - o] : 0);
        __syncthreads();
        s[t] = v;
        __syncthreads();
    }
    if (t < nb) bstart[t] = s[t] - tot;
    if (t == 0) bstart[nb] = E;
}
__global__ __launch_bounds__(256) void p2b_k(int* __restrict__ hist, const int* __restrict__ bstart) {
    __shared__ int s[GPART];
    const int b = blockIdx.x, t = threadIdx.x;
    const int v0 = hist[b * GPART + t], v1 = hist[b * GPART + 256 + t];
    s[t] = v0; s[256 + t] = v1;
    __syncthreads();
    for (int o = 1; o < GPART; o <<= 1) {
        const int a0 = s[t] + ((t >= o) ? s[t - o] : 0);
        const int a1 = s[256 + t] + ((256 + t >= o) ? s[256 + t - o] : 0);
        __syncthreads();
        s[t] = a0; s[256 + t] = a1;
        __syncthreads();
    }
    const int base = bstart[b];
    hist[b * GPART + t] = base + s[t] - v0;
    hist[b * GPART + 256 + t] = base + s[256 + t] - v1;
}
__global__ __launch_bounds__(BLK) void p3_part_k(const int* __restrict__ rows, const int* __restrict__ cols,
                                                 const int* __restrict__ hist, int2* __restrict__ pairs,
                                                 int E, int nb) {
    __shared__ int tail[MAXNB];
    const int tid = threadIdx.x, g = blockIdx.x;
    for (int b = tid; b < nb; b += BLK) tail[b] = hist[b * GPART + g];
    __syncthreads();
    const int chunk = (E + GPART - 1) / GPART;
    const int start = g * chunk, end = min(E, start + chunk);
    for (int e = start + tid; e < end; e += BLK) {
        const int r = rows[e], c = cols[e];
        const int pos = atomicAdd(&tail[c >> NBSHIFT], 1);
        pairs[pos] = make_int2(r, c);
    }
}
__global__ __launch_bounds__(BLK) void p4_fill_k(const int2* __restrict__ pairs, const int* __restrict__ bstart,
                                                 int* __restrict__ P, float* __restrict__ dinv,
                                                 int* __restrict__ srow, int n) {
    __shared__ int dh[1 << NBSHIFT];
    __shared__ int tl[1 << NBSHIFT];
    const int b = blockIdx.x, t = threadIdx.x;
    const int base = b << NBSHIFT;
    const int nnod = min(1 << NBSHIFT, n - base);
    const int lo = bstart[b], hi = bstart[b + 1];
    dh[t] = 0; dh[256 + t] = 0;
    __syncthreads();
    for (int e = lo + t; e < hi; e += BLK) atomicAdd(&dh[pairs[e].y - base], 1);
    __syncthreads();
    const int v0 = dh[t], v1 = dh[256 + t];
    tl[t] = v0; tl[256 + t] = v1;
    __syncthreads();
    for (int o = 1; o < (1 << NBSHIFT); o <<= 1) {
        const int a0 = tl[t] + ((t >= o) ? tl[t - o] : 0);
        const int a1 = tl[256 + t] + ((256 + t >= o) ? tl[256 + t - o] : 0);
        __syncthreads();
        tl[t] = a0; tl[256 + t] = a1;
        __syncthreads();
    }
    const int s0 = lo + tl[t] - v0;          // exclusive start of node base+t
    const int s1 = lo + tl[256 + t] - v1;
    __syncthreads();
    tl[t] = s0; tl[256 + t] = s1;
    if (t < nnod)       { P[base + t] = s0;       dinv[base + t] = rsqrtf((float)v0 + 1.0f); }
    if (256 + t < nnod) { P[base + 256 + t] = s1; dinv[base + 256 + t] = rsqrtf((float)v1 + 1.0f); }
    __syncthreads();
    for (int e = lo + t; e < hi; e += BLK) {
        const int2 pr = pairs[e];
        const int pos = atomicAdd(&tl[pr.y - base], 1);
        srow[pos] = pr.x;
    }
}

// ================= fp16-input gather: rows of Tp stored as __half ==================
__device__ __forceinline__ void addh(float2 A[4], const __half* p) {
    const float4 raw = ld4((const float*)p);
    const __half2* h = (const __half2*)&raw;
    const float2 f0 = __half22float2(h[0]);
    const float2 f1 = __half22float2(h[1]);
    const float2 f2 = __half22float2(h[2]);
    const float2 f3 = __half22float2(h[3]);
    A[0].x += f0.x; A[0].y += f0.y;
    A[1].x += f1.x; A[1].y += f1.y;
    A[2].x += f2.x; A[2].y += f2.y;
    A[3].x += f3.x; A[3].y += f3.y;
}

template<int WD, bool PRE, bool OUTH>
__global__ __launch_bounds__(BLK) void gatherh_k(const __half* __restrict__ Tp, const int* __restrict__ P,
                                                 const int* __restrict__ srow, const float* __restrict__ dinv,
                                                 const float* __restrict__ bin, void* __restrict__ outv,
                                                 int n, int E) {
    constexpr int LPN = WD / 8;   // lanes per node
    const long gid = (long)blockIdx.x * BLK + threadIdx.x;
    const int i = (int)(gid / LPN);
    if (i >= n) return;
    const int q = (int)(gid % LPN) * 8;
    const int start = P[i];
    const int end = (i + 1 < n) ? P[i + 1] : E;
    const float d = dinv[i];
    const __half* __restrict__ Tq = Tp + q;
    float2 A0[4], A1[4], A2[4], A3[4];
    {   // self-loop
        const float4 raw = ld4((const float*)(Tq + (long)i * WD));
        const __half2* h = (const __half2*)&raw;
        A0[0] = __half22float2(h[0]); A0[1] = __half22float2(h[1]);
        A0[2] = __half22float2(h[2]); A0[3] = __half22float2(h[3]);
    }
#pragma unroll
    for (int k = 0; k < 4; k++) {
        A1[k] = make_float2(0.f, 0.f); A2[k] = make_float2(0.f, 0.f); A3[k] = make_float2(0.f, 0.f);
    }
    int e = start;
    const int ea = min(end, (start + 3) & ~3);   // align srow to int4
    for (; e < ea; e++) addh(A0, Tq + (long)srow[e] * WD);
    for (; e + 8 <= end; e += 8) {
        const int4 j0 = *(const int4*)&srow[e];
        const int4 j1 = *(const int4*)&srow[e + 4];
        addh(A0, Tq + (long)j0.x * WD); addh(A1, Tq + (long)j0.y * WD);
        addh(A2, Tq + (long)j0.z * WD); addh(A3, Tq + (long)j0.w * WD);
        addh(A0, Tq + (long)j1.x * WD); addh(A1, Tq + (long)j1.y * WD);
        addh(A2, Tq + (long)j1.z * WD); addh(A3, Tq + (long)j1.w * WD);
    }
    if (e + 4 <= end) {
        const int4 j0 = *(const int4*)&srow[e];
        addh(A0, Tq + (long)j0.x * WD); addh(A1, Tq + (long)j0.y * WD);
        addh(A2, Tq + (long)j0.z * WD); addh(A3, Tq + (long)j0.w * WD);
        e += 4;
    }
    for (; e < end; e++) addh(A0, Tq + (long)srow[e] * WD);
#pragma unroll
    for (int k = 0; k < 4; k++) {
        A0[k].x += A1[k].x + A2[k].x + A3[k].x;
        A0[k].y += A1[k].y + A2[k].y + A3[k].y;
    }
    float v[8];
    v[0] = d * A0[0].x; v[1] = d * A0[0].y; v[2] = d * A0[1].x; v[3] = d * A0[1].y;
    v[4] = d * A0[2].x; v[5] = d * A0[2].y; v[6] = d * A0[3].x; v[7] = d * A0[3].y;
    if (PRE) {
        const float4 b0 = ld4(&bin[q]);
        const float4 b1 = ld4(&bin[q + 4]);
        v[0] = fmaxf(v[0] + b0.x, 0.f) * d; v[1] = fmaxf(v[1] + b0.y, 0.f) * d;
        v[2] = fmaxf(v[2] + b0.z, 0.f) * d; v[3] = fmaxf(v[3] + b0.w, 0.f) * d;
        v[4] = fmaxf(v[4] + b1.x, 0.f) * d; v[5] = fmaxf(v[5] + b1.y, 0.f) * d;
        v[6] = fmaxf(v[6] + b1.z, 0.f) * d; v[7] = fmaxf(v[7] + b1.w, 0.f) * d;
    }
    if (OUTH) {
        const __half2 h0 = __floats2half2_rn(v[0], v[1]);
        const __half2 h1 = __floats2half2_rn(v[2], v[3]);
        const __half2 h2 = __floats2half2_rn(v[4], v[5]);
        const __half2 h3 = __floats2half2_rn(v[6], v[7]);
        uint4 u;
        u.x = *(const unsigned int*)&h0; u.y = *(const unsigned int*)&h1;
        u.z = *(const unsigned int*)&h2; u.w = *(const unsigned int*)&h3;
        *(uint4*)((__half*)outv + (long)i * WD + q) = u;
    } else {
        float* out = (float*)outv;
        float4 v0, v1;
        v0.x = v[0]; v0.y = v[1]; v0.z = v[2]; v0.w = v[3];
        v1.x = v[4]; v1.y = v[5]; v1.z = v[6]; v1.w = v[7];
        *(float4*)&out[(long)i * WD + q] = v0;
        *(float4*)&out[(long)i * WD + q + 4] = v1;
    }
}

// ================= fp32 LDS-tiled GEMM (small layers L2-L5) =================
template<int FI, int FO, bool INB, bool OUTB, bool OUTRELU, bool OSC, bool OUTH>
__global__ __launch_bounds__(BLK) void gemm_k(const float* __restrict__ H, const float* __restrict__ Wm,
                                              const float* __restrict__ bin, const float* __restrict__ bout,
                                              const float* __restrict__ dinv, float* __restrict__ out, int n) {
    constexpr int COLT = FO / 4;
    constexpr int RTH  = BLK / COLT;
    constexpr int RPT  = (FO >= 64) ? 8 : 4;
    constexpr int ROWS = RTH * RPT;
    constexpr int KC   = (FI > 64) ? 64 : FI;
    constexpr int NKB  = FI / KC;

    __shared__ float Wl[KC * FO];
    __shared__ float Hl[ROWS * (KC + 1)];

    const int tid    = threadIdx.x;
    const int colIdx = tid % COLT;
    const int rowIdx = tid / COLT;
    const long rowBase = (long)blockIdx.x * ROWS;

    float4 acc[RPT];
#pragma unroll
    for (int i = 0; i < RPT; i++) acc[i] = make_float4(0.f, 0.f, 0.f, 0.f);

    for (int kb = 0; kb < NKB; kb++) {
        if (kb) __syncthreads();
        for (int f = tid * 4; f < KC * FO; f += BLK * 4) {
            const int kr = f / FO, c = f % FO;
            *(float4*)&Wl[kr * FO + c] = ld4(&Wm[(kb * KC + kr) * FO + c]);
        }
        for (int f = tid * 4; f < ROWS * KC; f += BLK * 4) {
            const int rr = f / KC, kk = f % KC;
            const long r = rowBase + rr;
            float4 v = make_float4(0.f, 0.f, 0.f, 0.f);
            if (r < n) v = ld4(&H[r * FI + kb * KC + kk]);
            if (INB) {
                float4 b4 = ld4(&bin[kb * KC + kk]);
                v.x = fmaxf(v.x + b4.x, 0.f); v.y = fmaxf(v.y + b4.y, 0.f);
                v.z = fmaxf(v.z + b4.z, 0.f); v.w = fmaxf(v.w + b4.w, 0.f);
            }
            float* dst = &Hl[rr * (KC + 1) + kk];
            dst[0] = v.x; dst[1] = v.y; dst[2] = v.z; dst[3] = v.w;
        }
        __syncthreads();
#pragma unroll 8
        for (int k = 0; k < KC; k++) {
            const float4 w4 = *(const float4*)&Wl[k * FO + 4 * colIdx];
#pragma unroll
            for (int i = 0; i < RPT; i++) {
                const float hv = Hl[(rowIdx * RPT + i) * (KC + 1) + k];
                acc[i].x = fmaf(hv, w4.x, acc[i].x);
                acc[i].y = fmaf(hv, w4.y, acc[i].y);
                acc[i].z = fmaf(hv, w4.z, acc[i].z);
                acc[i].w = fmaf(hv, w4.w, acc[i].w);
            }
        }
    }

    float4 bo = make_float4(0.f, 0.f, 0.f, 0.f);
    if (OUTB) bo = ld4(&bout[4 * colIdx]);
#pragma unroll
    for (int i = 0; i < RPT; i++) {
        const long r = rowBase + rowIdx * RPT + i;
        if (r < n) {
            float4 v = acc[i];
            if (OUTB) { v.x += bo.x; v.y += bo.y; v.z += bo.z; v.w += bo.w; }
            if (OUTRELU) {
                v.x = fmaxf(v.x, 0.f); v.y = fmaxf(v.y, 0.f);
                v.z = fmaxf(v.z, 0.f); v.w = fmaxf(v.w, 0.f);
            }
            if (OSC) {
                const float d = dinv[r];
                v.x *= d; v.y *= d; v.z *= d; v.w *= d;
            }
            if (OUTH) {
                const __half2 h01 = __floats2half2_rn(v.x, v.y);
                const __half2 h23 = __floats2half2_rn(v.z, v.w);
                uint2 u;
                u.x = *(const unsigned int*)&h01;
                u.y = *(const unsigned int*)&h23;
                *(uint2*)((__half*)out + r * FO + 4 * colIdx) = u;
            } else {
                *(float4*)&out[r * FO + 4 * colIdx] = v;
            }
        }
    }
}

// ================= W prep: fp32 KxFO -> fp16 FOxK, k-permuted per 32-block (one-shot) ======
// pk = (k & ~31) + 8*((k>>2)&3) + 4*((k>>4)&1) + (k&3): lane frag = one contiguous half8.
template<int K, int FO>
__global__ __launch_bounds__(BLK) void wprep_k(const float* __restrict__ Wm, _Float16* __restrict__ Wh) {
    const int f = (blockIdx.x * BLK + threadIdx.x) * 4;
    if (f >= K * FO) return;
    const int nn = f / K, k0 = f % K;          // k0 % 4 == 0
    const int blk = k0 & ~31, g = (k0 >> 2) & 3, h = (k0 >> 4) & 1;
    half4v w4;
#pragma unroll
    for (int c = 0; c < 4; c++) w4[c] = (_Float16)Wm[(k0 + c) * FO + nn];
    *(half4v*)&Wh[nn * K + blk + 8 * g + 4 * h] = w4;
}

// ================= MFMA fp16 GEMM (big layers). BM=64: 4 waves x 16 rows. ==================
// B from pre-permuted Wh (coalesced copy). Halved LDS vs BM=128 -> 3-5 blocks/CU, 2x grid.
// Frag layout v_mfma_f32_16x16x32_f16 (verified bit-identical in R5):
//   A/B: row|col = lane&15, k = (lane>>4)*4 + (j&3) + 16*(j>>2);  C/D: col=lane&15, row=(lane>>4)*4+reg.
template<int K, int FO, bool AH, bool OUTB, bool OUTRELU, bool OSC, bool OUTH>
__global__ __launch_bounds__(BLK) void mgemm_k(const void* __restrict__ Hv, const _Float16* __restrict__ Wh,
                                               const float* __restrict__ bout, const float* __restrict__ dinv,
                                               void* __restrict__ outv, int n) {
    constexpr int BM = 64;             // rows per block (4 waves x 16 rows)
    constexpr int KP = K + 8;          // padded row stride (halves); KP*2 is 16B-multiple
    constexpr int NT = FO / 16;        // 16-col tiles
    __shared__ _Float16 Al[BM * KP];
    __shared__ _Float16 Bl[FO * KP];

    const int tid = threadIdx.x;
    const long rowBase = (long)blockIdx.x * BM;

    // ---- stage B: coalesced 16B copies of pre-permuted Wh ----
    for (int f = tid * 8; f < K * FO; f += BLK * 8) {
        const int nn = f / K, k = f % K;       // k % 8 == 0
        *(uint4*)&Bl[nn * KP + k] = *(const uint4*)&Wh[f];
    }
    // ---- stage A (permute on the fly) ----
    if (AH) {
        const __half* Hp = (const __half*)Hv;
        for (int f = tid * 8; f < BM * K; f += BLK * 8) {
            const int rr = f / K, k0 = f % K;  // k0 % 8 == 0
            const long r = rowBase + rr;
            uint4 u = make_uint4(0u, 0u, 0u, 0u);
            if (r < n) u = *(const uint4*)&Hp[r * K + k0];
            const int blk = k0 & ~31, g0 = (k0 >> 2) & 3, h = (k0 >> 4) & 1;
            *(uint2*)&Al[rr * KP + blk + 8 * g0 + 4 * h] = make_uint2(u.x, u.y);
            *(uint2*)&Al[rr * KP + blk + 8 * (g0 + 1) + 4 * h] = make_uint2(u.z, u.w);
        }
    } else {
        const float* Hp = (const float*)Hv;
        for (int f = tid * 4; f < BM * K; f += BLK * 4) {
            const int rr = f / K, k0 = f % K;  // k0 % 4 == 0
            const long r = rowBase + rr;
            float4 v = make_float4(0.f, 0.f, 0.f, 0.f);
            if (r < n) v = ld4(&Hp[r * K + k0]);
            const int blk = k0 & ~31, g = (k0 >> 2) & 3, h = (k0 >> 4) & 1;
            half4v a4;
            a4[0] = (_Float16)v.x; a4[1] = (_Float16)v.y; a4[2] = (_Float16)v.z; a4[3] = (_Float16)v.w;
            *(half4v*)&Al[rr * KP + blk + 8 * g + 4 * h] = a4;
        }
    }
    __syncthreads();

    // ---- MFMA main loop: wave wv owns rows [wv*16, wv*16+16) x all FO cols ----
    const int wv = tid >> 6;
    const int lane = tid & 63;
    const int lr = lane & 15;
    const int lg = lane >> 4;
    const int wrow = wv * 16;

    const f32x4v vzero = {0.f, 0.f, 0.f, 0.f};
    f32x4v acc[NT];
#pragma unroll
    for (int t = 0; t < NT; t++) acc[t] = vzero;

#pragma unroll
    for (int ks = 0; ks < K / 32; ks++) {
        const int ko = ks * 32 + 8 * lg;
        const half8v a = *(const half8v*)&Al[(wrow + lr) * KP + ko];
#pragma unroll
        for (int nt = 0; nt < NT; nt++) {
            const half8v b = *(const half8v*)&Bl[(nt * 16 + lr) * KP + ko];
            acc[nt] = __builtin_amdgcn_mfma_f32_16x16x32_f16(a, b, acc[nt], 0, 0, 0);
        }
    }

    // ---- epilogue ----
    float bo[NT];
    if (OUTB) {
#pragma unroll
        for (int nt = 0; nt < NT; nt++) bo[nt] = bout[nt * 16 + lr];
    }
#pragma unroll
    for (int r = 0; r < 4; r++) {
        const long row = rowBase + wrow + lg * 4 + r;
        if (row < n) {
            const float d = OSC ? dinv[row] : 1.0f;
#pragma unroll
            for (int nt = 0; nt < NT; nt++) {
                float v = acc[nt][r];
                if (OUTB) v += bo[nt];
                if (OUTRELU) v = fmaxf(v, 0.f);
                if (OSC) v *= d;
                if (OUTH) ((__half*)outv)[row * FO + nt * 16 + lr] = __float2half_rn(v);
                else      ((float*)outv)[row * FO + nt * 16 + lr] = v;
            }
        }
    }
}

extern "C" void kernel_launch(void* const* d_in, const int* in_sizes, int n_in,
                              void* d_out, int out_size, void* d_ws, size_t ws_size,
                              hipStream_t stream)
{
    const float* x  = (const float*)d_in[0];
    const int*   ei = (const int*)d_in[1];
    const float* W1 = (const float*)d_in[3];  const float* b1 = (const float*)d_in[4];
    const float* W2 = (const float*)d_in[5];  const float* b2 = (const float*)d_in[6];
    const float* W3 = (const float*)d_in[7];  const float* b3 = (const float*)d_in[8];
    const float* W4 = (const float*)d_in[9];  const float* b4 = (const float*)d_in[10];
    const float* W5 = (const float*)d_in[11]; const float* b5 = (const float*)d_in[12];
    const float* W6 = (const float*)d_in[13]; const float* b6 = (const float*)d_in[14];
    const float* Wf = (const float*)d_in[15]; const float* bf = (const float*)d_in[16];

    const int n = in_sizes[0] / 128;
    const int E = in_sizes[1] / 2;
    const int* rows = ei;       // source j
    const int* cols = ei + E;   // target i

    // workspace layout — total (n + E + n + 128n + 128n)*4 = 116,000,000 B (proven safe).
    int*   P    = (int*)d_ws;                        // n ints
    int*   srow = P + n;                             // E ints (16B-aligned for n%4==0)
    float* dinv = (float*)(srow + E);                // n floats
    float* bufA = dinv + n;                          // n*128 floats
    float* bufB = bufA + (size_t)n * 128;            // n*128 floats
    // pre-layer aliases (dead before first use of bufA/bufB by the layer pipeline):
    int2*  pairs = (int2*)bufA;                      // E int2 = 25.6MB <= 51.2MB
    int*   hist  = (int*)bufB;                       // MAXNB*GPART ints = 409KB
    int*   bstart= hist + MAXNB * GPART;             // nb+1 ints
    // persistent fp16 pre-permuted weights: bufB bytes [25.6MB, 25.6MB+64KB).
    // Every layer use of bufB is <= n*64 floats (= n*128 halves) = bytes [0, 25.6MB) -> no overlap.
    _Float16* Wh1 = (_Float16*)(bufB + (size_t)n * 64);  // 128*64
    _Float16* Wh6 = Wh1 + 128 * 64;                      // 64*128
    _Float16* Whf = Wh6 + 64 * 128;                      // 128*128

    auto cdiv = [](long a, long b) { return (unsigned)((a + b - 1) / b); };
    const int nb = (n + (1 << NBSHIFT) - 1) >> NBSHIFT;

    // --- one-shot W prep (touches only the Wh hole + weights) ---
    wprep_k<128, 64><<<cdiv(128 * 64 / 4, BLK), BLK, 0, stream>>>(W1, Wh1);
    wprep_k<64, 128><<<cdiv(64 * 128 / 4, BLK), BLK, 0, stream>>>(W6, Wh6);
    wprep_k<128, 128><<<cdiv(128 * 128 / 4, BLK), BLK, 0, stream>>>(Wf, Whf);

    // --- CSR build (atomic-free radix partition) ---
    p1_hist_k<<<GPART, BLK, 0, stream>>>(cols, hist, E, nb);
    p2a_k<<<1, 256, 0, stream>>>(hist, bstart, nb, E);
    p2b_k<<<nb, 256, 0, stream>>>(hist, bstart);
    p3_part_k<<<GPART, BLK, 0, stream>>>(rows, cols, hist, pairs, E, nb);
    p4_fill_k<<<nb, BLK, 0, stream>>>(pairs, bstart, P, dinv, srow, n);

    // --- layers (all gather tables fp16; big GEMMs fp16-MFMA with fp32 accumulate) ---
    // L1 (MFMA): t1' = (x@W1)*dinv [fp16] ; a1 = gather_h(t1') -> fp32  [deferred: +b1, relu]
    mgemm_k<128, 64, false, false, false, true, true><<<cdiv(n, 64), BLK, 0, stream>>>(x, Wh1, nullptr, dinv, bufA, n);
    gatherh_k<64, false, false><<<cdiv((long)n * 8, BLK), BLK, 0, stream>>>((const __half*)bufA, P, srow, dinv, nullptr, bufB, n, E);

    // L2: t2' = (relu(a1+b1)@W2)*dinv [fp16] ; a2 = gather_h -> fp32    [deferred: +b2, relu]
    gemm_k<64, 32, true, false, false, true, true><<<cdiv(n, 128), BLK, 0, stream>>>(bufB, W2, b1, nullptr, dinv, bufA, n);
    gatherh_k<32, false, false><<<cdiv((long)n * 4, BLK), BLK, 0, stream>>>((const __half*)bufA, P, srow, dinv, nullptr, bufB, n, E);

    // L3: t3' = (relu(a2+b2)@W3)*dinv [fp16] ; gather w/ fused epilogue -> t4' = relu(a3+b3)*dinv [fp16]
    gemm_k<32, 16, true, false, false, true, true><<<cdiv(n, 256), BLK, 0, stream>>>(bufB, W3, b2, nullptr, dinv, bufA, n);
    gatherh_k<16, true, true><<<cdiv((long)n * 2, BLK), BLK, 0, stream>>>((const __half*)bufA, P, srow, dinv, b3, bufB, n, E);

    // L4: a4 = gather_h(t4') -> fp32 ; h4' = relu(a4@W4+b4)*dinv [fp16]
    gatherh_k<16, false, false><<<cdiv((long)n * 2, BLK), BLK, 0, stream>>>((const __half*)bufB, P, srow, dinv, nullptr, bufA, n, E);
    gemm_k<16, 32, false, true, true, true, true><<<cdiv(n, 128), BLK, 0, stream>>>(bufA, W4, nullptr, b4, dinv, bufB, n);

    // L5: a5 = gather_h(h4') -> fp32 ; h5' = relu(a5@W5+b5)*dinv [fp16]
    gatherh_k<32, false, false><<<cdiv((long)n * 4, BLK), BLK, 0, stream>>>((const __half*)bufB, P, srow, dinv, nullptr, bufA, n, E);
    gemm_k<32, 64, false, true, true, true, true><<<cdiv(n, 128), BLK, 0, stream>>>(bufA, W5, nullptr, b5, dinv, bufB, n);

    // L6: a6 = gather_h(h5') -> fp16 ; (MFMA) h6 = relu(a6@W6+b6) [fp16]
    gatherh_k<64, false, true><<<cdiv((long)n * 8, BLK), BLK, 0, stream>>>((const __half*)bufB, P, srow, dinv, nullptr, bufA, n, E);
    mgemm_k<64, 128, true, true, true, false, true><<<cdiv(n, 64), BLK, 0, stream>>>(bufA, Wh6, b6, nullptr, bufB, n);

    // final (MFMA): out = h6 @ Wf + bf  [fp32 out]
    mgemm_k<128, 128, true, true, false, false, false><<<cdiv(n, 64), BLK, 0, stream>>>(bufB, Whf, bf, nullptr, d_out, n);
}

// Round 11
// 600.151 us; speedup vs baseline: 1.3780x; 1.0182x over previous
//
#include <hip/hip_runtime.h>
#include <hip/hip_fp16.h>

#define BLK 256
#define NBSHIFT 7     // 128 nodes per bucket -> nb ~= 782 blocks (3/CU) for p4
#define MAXNB 800     // supports n <= 102400
#define GPART 512     // partition blocks

typedef _Float16 half4v __attribute__((ext_vector_type(4)));
typedef _Float16 half8v __attribute__((ext_vector_type(8)));
typedef float    f32x4v __attribute__((ext_vector_type(4)));

__device__ __forceinline__ float4 ld4(const float* p) { return *(const float4*)p; }

// ================= CSR build: atomic-free radix partition by col>>NBSHIFT =================
__global__ __launch_bounds__(BLK) void p1_hist_k(const int* __restrict__ cols, int* __restrict__ hist,
                                                 int E, int nb) {
    __shared__ int h[MAXNB];
    const int tid = threadIdx.x, g = blockIdx.x;
    for (int b = tid; b < nb; b += BLK) h[b] = 0;
    __syncthreads();
    const int chunk = (E + GPART - 1) / GPART;
    const int start = g * chunk, end = min(E, start + chunk);
    for (int e = start + tid; e < end; e += BLK) atomicAdd(&h[cols[e] >> NBSHIFT], 1);
    __syncthreads();
    for (int b = tid; b < nb; b += BLK) hist[b * GPART + g] = h[b];
}
// P2a-tot: per-bucket total over its GPART block-counts. grid = nb.
__global__ __launch_bounds__(256) void p2a_tot_k(const int* __restrict__ hist, int* __restrict__ tot) {
    __shared__ int s[256];
    const int b = blockIdx.x, t = threadIdx.x;
    s[t] = hist[b * GPART + t] + hist[b * GPART + 256 + t];
    __syncthreads();
    for (int o = 128; o > 0; o >>= 1) {
        if (t < o) s[t] += s[t + o];
        __syncthreads();
    }
    if (t == 0) tot[b] = s[0];
}
// P2a-scan: single-block exclusive scan over nb (<=1024) totals -> bstart[0..nb], bstart[nb]=E.
__global__ __launch_bounds__(256) void p2a_scan_k(const int* __restrict__ tot, int* __restrict__ bstart,
                                                  int nb, int E) {
    __shared__ int s[256];
    const int t = threadIdx.x;
    const int base = t * 4;
    int l0 = 0, l1 = 0, l2 = 0, l3 = 0;
    if (base < nb)     l0 = tot[base];
    if (base + 1 < nb) l1 = tot[base + 1];
    if (base + 2 < nb) l2 = tot[base + 2];
    if (base + 3 < nb) l3 = tot[base + 3];
    const int sum = l0 + l1 + l2 + l3;
    s[t] = sum;
    __syncthreads();
    for (int o = 1; o < 256; o <<= 1) {
        const int v = s[t] + ((t >= o) ? s[t - o] : 0);
        __syncthreads();
        s[t] = v;
        __syncthreads();
    }
    const int excl = s[t] - sum;
    if (base < nb)     bstart[base]     = excl;
    if (base + 1 < nb) bstart[base + 1] = excl + l0;
    if (base + 2 < nb) bstart[base + 2] = excl + l0 + l1;
    if (base + 3 < nb) bstart[base + 3] = excl + l0 + l1 + l2;
    if (t == 0) bstart[nb] = E;
}
// P2b: per-bucket exclusive scan over its GPART block-counts, +bstart -> absolute offsets (in place).
__global__ __launch_bounds__(256) void p2b_k(int* __restrict__ hist, const int* __restrict__ bstart) {
    __shared__ int s[GPART];
    const int b = blockIdx.x, t = threadIdx.x;
    const int v0 = hist[b * GPART + t], v1 = hist[b * GPART + 256 + t];
    s[t] = v0; s[256 + t] = v1;
    __syncthreads();
    for (int o = 1; o < GPART; o <<= 1) {
        const int a0 = s[t] + ((t >= o) ? s[t - o] : 0);
        const int a1 = s[256 + t] + ((256 + t >= o) ? s[256 + t - o] : 0);
        __syncthreads();
        s[t] = a0; s[256 + t] = a1;
        __syncthreads();
    }
    const int base = bstart[b];
    hist[b * GPART + t] = base + s[t] - v0;
    hist[b * GPART + 256 + t] = base + s[256 + t] - v1;
}
__global__ __launch_bounds__(BLK) void p3_part_k(const int* __restrict__ rows, const int* __restrict__ cols,
                                                 const int* __restrict__ hist, int2* __restrict__ pairs,
                                                 int E, int nb) {
    __shared__ int tail[MAXNB];
    const int tid = threadIdx.x, g = blockIdx.x;
    for (int b = tid; b < nb; b += BLK) tail[b] = hist[b * GPART + g];
    __syncthreads();
    const int chunk = (E + GPART - 1) / GPART;
    const int start = g * chunk, end = min(E, start + chunk);
    for (int e = start + tid; e < end; e += BLK) {
        const int r = rows[e], c = cols[e];
        const int pos = atomicAdd(&tail[c >> NBSHIFT], 1);
        pairs[pos] = make_int2(r, c);
    }
}
__global__ __launch_bounds__(BLK) void p4_fill_k(const int2* __restrict__ pairs, const int* __restrict__ bstart,
                                                 int* __restrict__ P, float* __restrict__ dinv,
                                                 int* __restrict__ srow, int n) {
    constexpr int NN = 1 << NBSHIFT;
    __shared__ int dh[NN];
    __shared__ int tl[NN];
    const int b = blockIdx.x, t = threadIdx.x;
    const int base = b << NBSHIFT;
    const int nnod = min(NN, n - base);
    const int lo = bstart[b], hi = bstart[b + 1];
    if (t < NN) dh[t] = 0;
    __syncthreads();
    for (int e = lo + t; e < hi; e += BLK) atomicAdd(&dh[pairs[e].y - base], 1);
    __syncthreads();
    const int v0 = (t < NN) ? dh[t] : 0;
    if (t < NN) tl[t] = v0;
    __syncthreads();
    for (int o = 1; o < NN; o <<= 1) {
        int a0 = 0;
        if (t < NN) a0 = tl[t] + ((t >= o) ? tl[t - o] : 0);
        __syncthreads();
        if (t < NN) tl[t] = a0;
        __syncthreads();
    }
    const int s0 = lo + ((t < NN) ? tl[t] : 0) - v0;   // exclusive start of node base+t
    __syncthreads();
    if (t < NN) tl[t] = s0;
    if (t < nnod) { P[base + t] = s0; dinv[base + t] = rsqrtf((float)v0 + 1.0f); }
    __syncthreads();
    for (int e = lo + t; e < hi; e += BLK) {
        const int2 pr = pairs[e];
        const int pos = atomicAdd(&tl[pr.y - base], 1);
        srow[pos] = pr.x;
    }
}

// ================= fp16-input gather: rows of Tp stored as __half ==================
__device__ __forceinline__ void addh(float2 A[4], const __half* p) {
    const float4 raw = ld4((const float*)p);
    const __half2* h = (const __half2*)&raw;
    const float2 f0 = __half22float2(h[0]);
    const float2 f1 = __half22float2(h[1]);
    const float2 f2 = __half22float2(h[2]);
    const float2 f3 = __half22float2(h[3]);
    A[0].x += f0.x; A[0].y += f0.y;
    A[1].x += f1.x; A[1].y += f1.y;
    A[2].x += f2.x; A[2].y += f2.y;
    A[3].x += f3.x; A[3].y += f3.y;
}

template<int WD, bool PRE, bool OUTH>
__global__ __launch_bounds__(BLK) void gatherh_k(const __half* __restrict__ Tp, const int* __restrict__ P,
                                                 const int* __restrict__ srow, const float* __restrict__ dinv,
                                                 const float* __restrict__ bin, void* __restrict__ outv,
                                                 int n, int E) {
    constexpr int LPN = WD / 8;   // lanes per node
    const long gid = (long)blockIdx.x * BLK + threadIdx.x;
    const int i = (int)(gid / LPN);
    if (i >= n) return;
    const int q = (int)(gid % LPN) * 8;
    const int start = P[i];
    const int end = (i + 1 < n) ? P[i + 1] : E;
    const float d = dinv[i];
    const __half* __restrict__ Tq = Tp + q;
    float2 A0[4], A1[4], A2[4], A3[4];
    {   // self-loop
        const float4 raw = ld4((const float*)(Tq + (long)i * WD));
        const __half2* h = (const __half2*)&raw;
        A0[0] = __half22float2(h[0]); A0[1] = __half22float2(h[1]);
        A0[2] = __half22float2(h[2]); A0[3] = __half22float2(h[3]);
    }
#pragma unroll
    for (int k = 0; k < 4; k++) {
        A1[k] = make_float2(0.f, 0.f); A2[k] = make_float2(0.f, 0.f); A3[k] = make_float2(0.f, 0.f);
    }
    int e = start;
    const int ea = min(end, (start + 3) & ~3);   // align srow to int4
    for (; e < ea; e++) addh(A0, Tq + (long)srow[e] * WD);
    for (; e + 8 <= end; e += 8) {
        const int4 j0 = *(const int4*)&srow[e];
        const int4 j1 = *(const int4*)&srow[e + 4];
        addh(A0, Tq + (long)j0.x * WD); addh(A1, Tq + (long)j0.y * WD);
        addh(A2, Tq + (long)j0.z * WD); addh(A3, Tq + (long)j0.w * WD);
        addh(A0, Tq + (long)j1.x * WD); addh(A1, Tq + (long)j1.y * WD);
        addh(A2, Tq + (long)j1.z * WD); addh(A3, Tq + (long)j1.w * WD);
    }
    if (e + 4 <= end) {
        const int4 j0 = *(const int4*)&srow[e];
        addh(A0, Tq + (long)j0.x * WD); addh(A1, Tq + (long)j0.y * WD);
        addh(A2, Tq + (long)j0.z * WD); addh(A3, Tq + (long)j0.w * WD);
        e += 4;
    }
    for (; e < end; e++) addh(A0, Tq + (long)srow[e] * WD);
#pragma unroll
    for (int k = 0; k < 4; k++) {
        A0[k].x += A1[k].x + A2[k].x + A3[k].x;
        A0[k].y += A1[k].y + A2[k].y + A3[k].y;
    }
    float v[8];
    v[0] = d * A0[0].x; v[1] = d * A0[0].y; v[2] = d * A0[1].x; v[3] = d * A0[1].y;
    v[4] = d * A0[2].x; v[5] = d * A0[2].y; v[6] = d * A0[3].x; v[7] = d * A0[3].y;
    if (PRE) {
        const float4 b0 = ld4(&bin[q]);
        const float4 b1 = ld4(&bin[q + 4]);
        v[0] = fmaxf(v[0] + b0.x, 0.f) * d; v[1] = fmaxf(v[1] + b0.y, 0.f) * d;
        v[2] = fmaxf(v[2] + b0.z, 0.f) * d; v[3] = fmaxf(v[3] + b0.w, 0.f) * d;
        v[4] = fmaxf(v[4] + b1.x, 0.f) * d; v[5] = fmaxf(v[5] + b1.y, 0.f) * d;
        v[6] = fmaxf(v[6] + b1.z, 0.f) * d; v[7] = fmaxf(v[7] + b1.w, 0.f) * d;
    }
    if (OUTH) {
        const __half2 h0 = __floats2half2_rn(v[0], v[1]);
        const __half2 h1 = __floats2half2_rn(v[2], v[3]);
        const __half2 h2 = __floats2half2_rn(v[4], v[5]);
        const __half2 h3 = __floats2half2_rn(v[6], v[7]);
        uint4 u;
        u.x = *(const unsigned int*)&h0; u.y = *(const unsigned int*)&h1;
        u.z = *(const unsigned int*)&h2; u.w = *(const unsigned int*)&h3;
        *(uint4*)((__half*)outv + (long)i * WD + q) = u;
    } else {
        float* out = (float*)outv;
        float4 v0, v1;
        v0.x = v[0]; v0.y = v[1]; v0.z = v[2]; v0.w = v[3];
        v1.x = v[4]; v1.y = v[5]; v1.z = v[6]; v1.w = v[7];
        *(float4*)&out[(long)i * WD + q] = v0;
        *(float4*)&out[(long)i * WD + q + 4] = v1;
    }
}

// ================= fp32 LDS-tiled GEMM (small layers L2-L5) =================
template<int FI, int FO, bool INB, bool OUTB, bool OUTRELU, bool OSC, bool OUTH>
__global__ __launch_bounds__(BLK) void gemm_k(const float* __restrict__ H, const float* __restrict__ Wm,
                                              const float* __restrict__ bin, const float* __restrict__ bout,
                                              const float* __restrict__ dinv, float* __restrict__ out, int n) {
    constexpr int COLT = FO / 4;
    constexpr int RTH  = BLK / COLT;
    constexpr int RPT  = (FO >= 64) ? 8 : 4;
    constexpr int ROWS = RTH * RPT;
    constexpr int KC   = (FI > 64) ? 64 : FI;
    constexpr int NKB  = FI / KC;

    __shared__ float Wl[KC * FO];
    __shared__ float Hl[ROWS * (KC + 1)];

    const int tid    = threadIdx.x;
    const int colIdx = tid % COLT;
    const int rowIdx = tid / COLT;
    const long rowBase = (long)blockIdx.x * ROWS;

    float4 acc[RPT];
#pragma unroll
    for (int i = 0; i < RPT; i++) acc[i] = make_float4(0.f, 0.f, 0.f, 0.f);

    for (int kb = 0; kb < NKB; kb++) {
        if (kb) __syncthreads();
        for (int f = tid * 4; f < KC * FO; f += BLK * 4) {
            const int kr = f / FO, c = f % FO;
            *(float4*)&Wl[kr * FO + c] = ld4(&Wm[(kb * KC + kr) * FO + c]);
        }
        for (int f = tid * 4; f < ROWS * KC; f += BLK * 4) {
            const int rr = f / KC, kk = f % KC;
            const long r = rowBase + rr;
            float4 v = make_float4(0.f, 0.f, 0.f, 0.f);
            if (r < n) v = ld4(&H[r * FI + kb * KC + kk]);
            if (INB) {
                float4 b4 = ld4(&bin[kb * KC + kk]);
                v.x = fmaxf(v.x + b4.x, 0.f); v.y = fmaxf(v.y + b4.y, 0.f);
                v.z = fmaxf(v.z + b4.z, 0.f); v.w = fmaxf(v.w + b4.w, 0.f);
            }
            float* dst = &Hl[rr * (KC + 1) + kk];
            dst[0] = v.x; dst[1] = v.y; dst[2] = v.z; dst[3] = v.w;
        }
        __syncthreads();
#pragma unroll 8
        for (int k = 0; k < KC; k++) {
            const float4 w4 = *(const float4*)&Wl[k * FO + 4 * colIdx];
#pragma unroll
            for (int i = 0; i < RPT; i++) {
                const float hv = Hl[(rowIdx * RPT + i) * (KC + 1) + k];
                acc[i].x = fmaf(hv, w4.x, acc[i].x);
                acc[i].y = fmaf(hv, w4.y, acc[i].y);
                acc[i].z = fmaf(hv, w4.z, acc[i].z);
                acc[i].w = fmaf(hv, w4.w, acc[i].w);
            }
        }
    }

    float4 bo = make_float4(0.f, 0.f, 0.f, 0.f);
    if (OUTB) bo = ld4(&bout[4 * colIdx]);
#pragma unroll
    for (int i = 0; i < RPT; i++) {
        const long r = rowBase + rowIdx * RPT + i;
        if (r < n) {
            float4 v = acc[i];
            if (OUTB) { v.x += bo.x; v.y += bo.y; v.z += bo.z; v.w += bo.w; }
            if (OUTRELU) {
                v.x = fmaxf(v.x, 0.f); v.y = fmaxf(v.y, 0.f);
                v.z = fmaxf(v.z, 0.f); v.w = fmaxf(v.w, 0.f);
            }
            if (OSC) {
                const float d = dinv[r];
                v.x *= d; v.y *= d; v.z *= d; v.w *= d;
            }
            if (OUTH) {
                const __half2 h01 = __floats2half2_rn(v.x, v.y);
                const __half2 h23 = __floats2half2_rn(v.z, v.w);
                uint2 u;
                u.x = *(const unsigned int*)&h01;
                u.y = *(const unsigned int*)&h23;
                *(uint2*)((__half*)out + r * FO + 4 * colIdx) = u;
            } else {
                *(float4*)&out[r * FO + 4 * colIdx] = v;
            }
        }
    }
}

// ================= W prep: fp32 KxFO -> fp16 FOxK, k-permuted per 32-block (one-shot) ======
// pk = (k & ~31) + 8*((k>>2)&3) + 4*((k>>4)&1) + (k&3): lane frag = one contiguous half8.
template<int K, int FO>
__global__ __launch_bounds__(BLK) void wprep_k(const float* __restrict__ Wm, _Float16* __restrict__ Wh) {
    const int f = (blockIdx.x * BLK + threadIdx.x) * 4;
    if (f >= K * FO) return;
    const int nn = f / K, k0 = f % K;          // k0 % 4 == 0
    const int blk = k0 & ~31, g = (k0 >> 2) & 3, h = (k0 >> 4) & 1;
    half4v w4;
#pragma unroll
    for (int c = 0; c < 4; c++) w4[c] = (_Float16)Wm[(k0 + c) * FO + nn];
    *(half4v*)&Wh[nn * K + blk + 8 * g + 4 * h] = w4;
}

// ================= MFMA fp16 GEMM (big layers). BM=64: 4 waves x 16 rows. ==================
// B from pre-permuted Wh (coalesced copy). Frag layout v_mfma_f32_16x16x32_f16 (R5-verified):
//   A/B: row|col = lane&15, k = (lane>>4)*4 + (j&3) + 16*(j>>2);  C/D: col=lane&15, row=(lane>>4)*4+reg.
template<int K, int FO, bool AH, bool OUTB, bool OUTRELU, bool OSC, bool OUTH>
__global__ __launch_bounds__(BLK) void mgemm_k(const void* __restrict__ Hv, const _Float16* __restrict__ Wh,
                                               const float* __restrict__ bout, const float* __restrict__ dinv,
                                               void* __restrict__ outv, int n) {
    constexpr int BM = 64;             // rows per block (4 waves x 16 rows)
    constexpr int KP = K + 8;          // padded row stride (halves); KP*2 is 16B-multiple
    constexpr int NT = FO / 16;        // 16-col tiles
    __shared__ _Float16 Al[BM * KP];
    __shared__ _Float16 Bl[FO * KP];

    const int tid = threadIdx.x;
    const long rowBase = (long)blockIdx.x * BM;

    // ---- stage B: coalesced 16B copies of pre-permuted Wh ----
    for (int f = tid * 8; f < K * FO; f += BLK * 8) {
        const int nn = f / K, k = f % K;       // k % 8 == 0
        *(uint4*)&Bl[nn * KP + k] = *(const uint4*)&Wh[f];
    }
    // ---- stage A (permute on the fly) ----
    if (AH) {
        const __half* Hp = (const __half*)Hv;
        for (int f = tid * 8; f < BM * K; f += BLK * 8) {
            const int rr = f / K, k0 = f % K;  // k0 % 8 == 0
            const long r = rowBase + rr;
            uint4 u = make_uint4(0u, 0u, 0u, 0u);
            if (r < n) u = *(const uint4*)&Hp[r * K + k0];
            const int blk = k0 & ~31, g0 = (k0 >> 2) & 3, h = (k0 >> 4) & 1;
            *(uint2*)&Al[rr * KP + blk + 8 * g0 + 4 * h] = make_uint2(u.x, u.y);
            *(uint2*)&Al[rr * KP + blk + 8 * (g0 + 1) + 4 * h] = make_uint2(u.z, u.w);
        }
    } else {
        const float* Hp = (const float*)Hv;
        for (int f = tid * 4; f < BM * K; f += BLK * 4) {
            const int rr = f / K, k0 = f % K;  // k0 % 4 == 0
            const long r = rowBase + rr;
            float4 v = make_float4(0.f, 0.f, 0.f, 0.f);
            if (r < n) v = ld4(&Hp[r * K + k0]);
            const int blk = k0 & ~31, g = (k0 >> 2) & 3, h = (k0 >> 4) & 1;
            half4v a4;
            a4[0] = (_Float16)v.x; a4[1] = (_Float16)v.y; a4[2] = (_Float16)v.z; a4[3] = (_Float16)v.w;
            *(half4v*)&Al[rr * KP + blk + 8 * g + 4 * h] = a4;
        }
    }
    __syncthreads();

    // ---- MFMA main loop: wave wv owns rows [wv*16, wv*16+16) x all FO cols ----
    const int wv = tid >> 6;
    const int lane = tid & 63;
    const int lr = lane & 15;
    const int lg = lane >> 4;
    const int wrow = wv * 16;

    const f32x4v vzero = {0.f, 0.f, 0.f, 0.f};
    f32x4v acc[NT];
#pragma unroll
    for (int t = 0; t < NT; t++) acc[t] = vzero;

#pragma unroll
    for (int ks = 0; ks < K / 32; ks++) {
        const int ko = ks * 32 + 8 * lg;
        const half8v a = *(const half8v*)&Al[(wrow + lr) * KP + ko];
#pragma unroll
        for (int nt = 0; nt < NT; nt++) {
            const half8v b = *(const half8v*)&Bl[(nt * 16 + lr) * KP + ko];
            acc[nt] = __builtin_amdgcn_mfma_f32_16x16x32_f16(a, b, acc[nt], 0, 0, 0);
        }
    }

    // ---- epilogue ----
    float bo[NT];
    if (OUTB) {
#pragma unroll
        for (int nt = 0; nt < NT; nt++) bo[nt] = bout[nt * 16 + lr];
    }
#pragma unroll
    for (int r = 0; r < 4; r++) {
        const long row = rowBase + wrow + lg * 4 + r;
        if (row < n) {
            const float d = OSC ? dinv[row] : 1.0f;
#pragma unroll
            for (int nt = 0; nt < NT; nt++) {
                float v = acc[nt][r];
                if (OUTB) v += bo[nt];
                if (OUTRELU) v = fmaxf(v, 0.f);
                if (OSC) v *= d;
                if (OUTH) ((__half*)outv)[row * FO + nt * 16 + lr] = __float2half_rn(v);
                else      ((float*)outv)[row * FO + nt * 16 + lr] = v;
            }
        }
    }
}

extern "C" void kernel_launch(void* const* d_in, const int* in_sizes, int n_in,
                              void* d_out, int out_size, void* d_ws, size_t ws_size,
                              hipStream_t stream)
{
    const float* x  = (const float*)d_in[0];
    const int*   ei = (const int*)d_in[1];
    const float* W1 = (const float*)d_in[3];  const float* b1 = (const float*)d_in[4];
    const float* W2 = (const float*)d_in[5];  const float* b2 = (const float*)d_in[6];
    const float* W3 = (const float*)d_in[7];  const float* b3 = (const float*)d_in[8];
    const float* W4 = (const float*)d_in[9];  const float* b4 = (const float*)d_in[10];
    const float* W5 = (const float*)d_in[11]; const float* b5 = (const float*)d_in[12];
    const float* W6 = (const float*)d_in[13]; const float* b6 = (const float*)d_in[14];
    const float* Wf = (const float*)d_in[15]; const float* bf = (const float*)d_in[16];

    const int n = in_sizes[0] / 128;
    const int E = in_sizes[1] / 2;
    const int* rows = ei;       // source j
    const int* cols = ei + E;   // target i

    // workspace layout — total (n + E + n + 128n + 128n)*4 = 116,000,000 B (proven safe).
    int*   P    = (int*)d_ws;                        // n ints
    int*   srow = P + n;                             // E ints (16B-aligned for n%4==0)
    float* dinv = (float*)(srow + E);                // n floats
    float* bufA = dinv + n;                          // n*128 floats
    float* bufB = bufA + (size_t)n * 128;            // n*128 floats
    // pre-layer aliases (dead before first use of bufA/bufB by the layer pipeline):
    int2*  pairs = (int2*)bufA;                      // E int2 = 25.6MB <= 51.2MB
    int*   hist  = (int*)bufB;                       // MAXNB*GPART ints = 1.64MB
    int*   bstart= hist + MAXNB * GPART;             // nb+1 ints (<= 1024+1)
    int*   tot   = bstart + 1032;                    // nb ints
    // persistent fp16 pre-permuted weights: bufB bytes [25.6MB, 25.6MB+64KB).
    // Every layer use of bufB is <= n*64 floats (= n*128 halves) = bytes [0, 25.6MB) -> no overlap.
    _Float16* Wh1 = (_Float16*)(bufB + (size_t)n * 64);  // 128*64
    _Float16* Wh6 = Wh1 + 128 * 64;                      // 64*128
    _Float16* Whf = Wh6 + 64 * 128;                      // 128*128

    auto cdiv = [](long a, long b) { return (unsigned)((a + b - 1) / b); };
    const int nb = (n + (1 << NBSHIFT) - 1) >> NBSHIFT;

    // --- one-shot W prep (touches only the Wh hole + weights) ---
    wprep_k<128, 64><<<cdiv(128 * 64 / 4, BLK), BLK, 0, stream>>>(W1, Wh1);
    wprep_k<64, 128><<<cdiv(64 * 128 / 4, BLK), BLK, 0, stream>>>(W6, Wh6);
    wprep_k<128, 128><<<cdiv(128 * 128 / 4, BLK), BLK, 0, stream>>>(Wf, Whf);

    // --- CSR build (atomic-free radix partition, 128-node buckets) ---
    p1_hist_k<<<GPART, BLK, 0, stream>>>(cols, hist, E, nb);
    p2a_tot_k<<<nb, 256, 0, stream>>>(hist, tot);
    p2a_scan_k<<<1, 256, 0, stream>>>(tot, bstart, nb, E);
    p2b_k<<<nb, 256, 0, stream>>>(hist, bstart);
    p3_part_k<<<GPART, BLK, 0, stream>>>(rows, cols, hist, pairs, E, nb);
    p4_fill_k<<<nb, BLK, 0, stream>>>(pairs, bstart, P, dinv, srow, n);

    // --- layers (all gather tables fp16; big GEMMs fp16-MFMA with fp32 accumulate) ---
    // L1 (MFMA): t1' = (x@W1)*dinv [fp16] ; a1 = gather_h(t1') -> fp32  [deferred: +b1, relu]
    mgemm_k<128, 64, false, false, false, true, true><<<cdiv(n, 64), BLK, 0, stream>>>(x, Wh1, nullptr, dinv, bufA, n);
    gatherh_k<64, false, false><<<cdiv((long)n * 8, BLK), BLK, 0, stream>>>((const __half*)bufA, P, srow, dinv, nullptr, bufB, n, E);

    // L2: t2' = (relu(a1+b1)@W2)*dinv [fp16] ; a2 = gather_h -> fp32    [deferred: +b2, relu]
    gemm_k<64, 32, true, false, false, true, true><<<cdiv(n, 128), BLK, 0, stream>>>(bufB, W2, b1, nullptr, dinv, bufA, n);
    gatherh_k<32, false, false><<<cdiv((long)n * 4, BLK), BLK, 0, stream>>>((const __half*)bufA, P, srow, dinv, nullptr, bufB, n, E);

    // L3: t3' = (relu(a2+b2)@W3)*dinv [fp16] ; gather w/ fused epilogue -> t4' = relu(a3+b3)*dinv [fp16]
    gemm_k<32, 16, true, false, false, true, true><<<cdiv(n, 256), BLK, 0, stream>>>(bufB, W3, b2, nullptr, dinv, bufA, n);
    gatherh_k<16, true, true><<<cdiv((long)n * 2, BLK), BLK, 0, stream>>>((const __half*)bufA, P, srow, dinv, b3, bufB, n, E);

    // L4: a4 = gather_h(t4') -> fp32 ; h4' = relu(a4@W4+b4)*dinv [fp16]
    gatherh_k<16, false, false><<<cdiv((long)n * 2, BLK), BLK, 0, stream>>>((const __half*)bufB, P, srow, dinv, nullptr, bufA, n, E);
    gemm_k<16, 32, false, true, true, true, true><<<cdiv(n, 128), BLK, 0, stream>>>(bufA, W4, nullptr, b4, dinv, bufB, n);

    // L5: a5 = gather_h(h4') -> fp32 ; h5' = relu(a5@W5+b5)*dinv [fp16]
    gatherh_k<32, false, false><<<cdiv((long)n * 4, BLK), BLK, 0, stream>>>((const __half*)bufB, P, srow, dinv, nullptr, bufA, n, E);
    gemm_k<32, 64, false, true, true, true, true><<<cdiv(n, 128), BLK, 0, stream>>>(bufA, W5, nullptr, b5, dinv, bufB, n);

    // L6: a6 = gather_h(h5') -> fp16 ; (MFMA) h6 = relu(a6@W6+b6) [fp16]
    gatherh_k<64, false, true><<<cdiv((long)n * 8, BLK), BLK, 0, stream>>>((const __half*)bufB, P, srow, dinv, nullptr, bufA, n, E);
    mgemm_k<64, 128, true, true, true, false, true><<<cdiv(n, 64), BLK, 0, stream>>>(bufA, Wh6, b6, nullptr, bufB, n);

    // final (MFMA): out = h6 @ Wf + bf  [fp32 out]
    mgemm_k<128, 128, true, true, false, false, false><<<cdiv(n, 64), BLK, 0, stream>>>(bufB, Whf, bf, nullptr, d_out, n);
}

// Round 12
// 598.193 us; speedup vs baseline: 1.3825x; 1.0033x over previous
//
#include <hip/hip_runtime.h>
#include <hip/hip_fp16.h>

#define BLK 256
#define NBSHIFT 7     // 128 nodes per bucket -> nb ~= 782 blocks (3/CU) for p4
#define MAXNB 800     // supports n <= 102400
#define GPART 512     // partition blocks
// packed edge: (local<<17)|row ; requires n < 131072 and NBSHIFT <= 7+ (local < 128)

typedef _Float16 half4v __attribute__((ext_vector_type(4)));
typedef _Float16 half8v __attribute__((ext_vector_type(8)));
typedef float    f32x4v __attribute__((ext_vector_type(4)));

__device__ __forceinline__ float4 ld4(const float* p) { return *(const float4*)p; }

// ================= CSR build: atomic-free radix partition by col>>NBSHIFT =================
__global__ __launch_bounds__(BLK) void p1_hist_k(const int* __restrict__ cols, int* __restrict__ hist,
                                                 int E, int nb) {
    __shared__ int h[MAXNB];
    const int tid = threadIdx.x, g = blockIdx.x;
    for (int b = tid; b < nb; b += BLK) h[b] = 0;
    __syncthreads();
    const int chunk = (E + GPART - 1) / GPART;
    const int start = g * chunk, end = min(E, start + chunk);
    for (int e = start + tid; e < end; e += BLK) atomicAdd(&h[cols[e] >> NBSHIFT], 1);
    __syncthreads();
    for (int b = tid; b < nb; b += BLK) hist[b * GPART + g] = h[b];
}
// P2a-tot: per-bucket total over its GPART block-counts. grid = nb.
__global__ __launch_bounds__(256) void p2a_tot_k(const int* __restrict__ hist, int* __restrict__ tot) {
    __shared__ int s[256];
    const int b = blockIdx.x, t = threadIdx.x;
    s[t] = hist[b * GPART + t] + hist[b * GPART + 256 + t];
    __syncthreads();
    for (int o = 128; o > 0; o >>= 1) {
        if (t < o) s[t] += s[t + o];
        __syncthreads();
    }
    if (t == 0) tot[b] = s[0];
}
// P2a-scan: single-block exclusive scan over nb (<=1024) totals -> bstart[0..nb], bstart[nb]=E.
__global__ __launch_bounds__(256) void p2a_scan_k(const int* __restrict__ tot, int* __restrict__ bstart,
                                                  int nb, int E) {
    __shared__ int s[256];
    const int t = threadIdx.x;
    const int base = t * 4;
    int l0 = 0, l1 = 0, l2 = 0, l3 = 0;
    if (base < nb)     l0 = tot[base];
    if (base + 1 < nb) l1 = tot[base + 1];
    if (base + 2 < nb) l2 = tot[base + 2];
    if (base + 3 < nb) l3 = tot[base + 3];
    const int sum = l0 + l1 + l2 + l3;
    s[t] = sum;
    __syncthreads();
    for (int o = 1; o < 256; o <<= 1) {
        const int v = s[t] + ((t >= o) ? s[t - o] : 0);
        __syncthreads();
        s[t] = v;
        __syncthreads();
    }
    const int excl = s[t] - sum;
    if (base < nb)     bstart[base]     = excl;
    if (base + 1 < nb) bstart[base + 1] = excl + l0;
    if (base + 2 < nb) bstart[base + 2] = excl + l0 + l1;
    if (base + 3 < nb) bstart[base + 3] = excl + l0 + l1 + l2;
    if (t == 0) bstart[nb] = E;
}
// P2b: per-bucket exclusive scan over its GPART block-counts, +bstart -> absolute offsets (in place).
__global__ __launch_bounds__(256) void p2b_k(int* __restrict__ hist, const int* __restrict__ bstart) {
    __shared__ int s[GPART];
    const int b = blockIdx.x, t = threadIdx.x;
    const int v0 = hist[b * GPART + t], v1 = hist[b * GPART + 256 + t];
    s[t] = v0; s[256 + t] = v1;
    __syncthreads();
    for (int o = 1; o < GPART; o <<= 1) {
        const int a0 = s[t] + ((t >= o) ? s[t - o] : 0);
        const int a1 = s[256 + t] + ((256 + t >= o) ? s[256 + t - o] : 0);
        __syncthreads();
        s[t] = a0; s[256 + t] = a1;
        __syncthreads();
    }
    const int base = bstart[b];
    hist[b * GPART + t] = base + s[t] - v0;
    hist[b * GPART + 256 + t] = base + s[256 + t] - v1;
}
// P3: partition edges into packed ints (local<<17)|row, sorted by bucket.
__global__ __launch_bounds__(BLK) void p3_part_k(const int* __restrict__ rows, const int* __restrict__ cols,
                                                 const int* __restrict__ hist, int* __restrict__ pairs,
                                                 int E, int nb) {
    __shared__ int tail[MAXNB];
    const int tid = threadIdx.x, g = blockIdx.x;
    for (int b = tid; b < nb; b += BLK) tail[b] = hist[b * GPART + g];
    __syncthreads();
    const int chunk = (E + GPART - 1) / GPART;
    const int start = g * chunk, end = min(E, start + chunk);
    for (int e = start + tid; e < end; e += BLK) {
        const int r = rows[e], c = cols[e];
        const int pos = atomicAdd(&tail[c >> NBSHIFT], 1);
        pairs[pos] = ((c & ((1 << NBSHIFT) - 1)) << 17) | r;
    }
}
__global__ __launch_bounds__(BLK) void p4_fill_k(const int* __restrict__ pairs, const int* __restrict__ bstart,
                                                 int* __restrict__ P, float* __restrict__ dinv,
                                                 int* __restrict__ srow, int n) {
    constexpr int NN = 1 << NBSHIFT;
    __shared__ int dh[NN];
    __shared__ int tl[NN];
    const int b = blockIdx.x, t = threadIdx.x;
    const int base = b << NBSHIFT;
    const int nnod = min(NN, n - base);
    const int lo = bstart[b], hi = bstart[b + 1];
    if (t < NN) dh[t] = 0;
    __syncthreads();
    for (int e = lo + t; e < hi; e += BLK) atomicAdd(&dh[((unsigned)pairs[e]) >> 17], 1);
    __syncthreads();
    const int v0 = (t < NN) ? dh[t] : 0;
    if (t < NN) tl[t] = v0;
    __syncthreads();
    for (int o = 1; o < NN; o <<= 1) {
        int a0 = 0;
        if (t < NN) a0 = tl[t] + ((t >= o) ? tl[t - o] : 0);
        __syncthreads();
        if (t < NN) tl[t] = a0;
        __syncthreads();
    }
    const int s0 = lo + ((t < NN) ? tl[t] : 0) - v0;   // exclusive start of node base+t
    __syncthreads();
    if (t < NN) tl[t] = s0;
    if (t < nnod) { P[base + t] = s0; dinv[base + t] = rsqrtf((float)v0 + 1.0f); }
    __syncthreads();
    for (int e = lo + t; e < hi; e += BLK) {
        const int pv = pairs[e];
        const int pos = atomicAdd(&tl[((unsigned)pv) >> 17], 1);
        srow[pos] = pv & 0x1FFFF;
    }
}

// ================= fp16-input gather: rows of Tp stored as __half ==================
__device__ __forceinline__ void addh(float2 A[4], const __half* p) {
    const float4 raw = ld4((const float*)p);
    const __half2* h = (const __half2*)&raw;
    const float2 f0 = __half22float2(h[0]);
    const float2 f1 = __half22float2(h[1]);
    const float2 f2 = __half22float2(h[2]);
    const float2 f3 = __half22float2(h[3]);
    A[0].x += f0.x; A[0].y += f0.y;
    A[1].x += f1.x; A[1].y += f1.y;
    A[2].x += f2.x; A[2].y += f2.y;
    A[3].x += f3.x; A[3].y += f3.y;
}

template<int WD, bool PRE, bool OUTH>
__global__ __launch_bounds__(BLK) void gatherh_k(const __half* __restrict__ Tp, const int* __restrict__ P,
                                                 const int* __restrict__ srow, const float* __restrict__ dinv,
                                                 const float* __restrict__ bin, void* __restrict__ outv,
                                                 int n, int E) {
    constexpr int LPN = WD / 8;   // lanes per node
    const long gid = (long)blockIdx.x * BLK + threadIdx.x;
    const int i = (int)(gid / LPN);
    if (i >= n) return;
    const int q = (int)(gid % LPN) * 8;
    const int start = P[i];
    const int end = (i + 1 < n) ? P[i + 1] : E;
    const float d = dinv[i];
    const __half* __restrict__ Tq = Tp + q;
    float2 A0[4], A1[4], A2[4], A3[4];
    {   // self-loop
        const float4 raw = ld4((const float*)(Tq + (long)i * WD));
        const __half2* h = (const __half2*)&raw;
        A0[0] = __half22float2(h[0]); A0[1] = __half22float2(h[1]);
        A0[2] = __half22float2(h[2]); A0[3] = __half22float2(h[3]);
    }
#pragma unroll
    for (int k = 0; k < 4; k++) {
        A1[k] = make_float2(0.f, 0.f); A2[k] = make_float2(0.f, 0.f); A3[k] = make_float2(0.f, 0.f);
    }
    int e = start;
    const int ea = min(end, (start + 3) & ~3);   // align srow to int4
    for (; e < ea; e++) addh(A0, Tq + (long)srow[e] * WD);
    for (; e + 8 <= end; e += 8) {
        const int4 j0 = *(const int4*)&srow[e];
        const int4 j1 = *(const int4*)&srow[e + 4];
        addh(A0, Tq + (long)j0.x * WD); addh(A1, Tq + (long)j0.y * WD);
        addh(A2, Tq + (long)j0.z * WD); addh(A3, Tq + (long)j0.w * WD);
        addh(A0, Tq + (long)j1.x * WD); addh(A1, Tq + (long)j1.y * WD);
        addh(A2, Tq + (long)j1.z * WD); addh(A3, Tq + (long)j1.w * WD);
    }
    if (e + 4 <= end) {
        const int4 j0 = *(const int4*)&srow[e];
        addh(A0, Tq + (long)j0.x * WD); addh(A1, Tq + (long)j0.y * WD);
        addh(A2, Tq + (long)j0.z * WD); addh(A3, Tq + (long)j0.w * WD);
        e += 4;
    }
    for (; e < end; e++) addh(A0, Tq + (long)srow[e] * WD);
#pragma unroll
    for (int k = 0; k < 4; k++) {
        A0[k].x += A1[k].x + A2[k].x + A3[k].x;
        A0[k].y += A1[k].y + A2[k].y + A3[k].y;
    }
    float v[8];
    v[0] = d * A0[0].x; v[1] = d * A0[0].y; v[2] = d * A0[1].x; v[3] = d * A0[1].y;
    v[4] = d * A0[2].x; v[5] = d * A0[2].y; v[6] = d * A0[3].x; v[7] = d * A0[3].y;
    if (PRE) {
        const float4 b0 = ld4(&bin[q]);
        const float4 b1 = ld4(&bin[q + 4]);
        v[0] = fmaxf(v[0] + b0.x, 0.f) * d; v[1] = fmaxf(v[1] + b0.y, 0.f) * d;
        v[2] = fmaxf(v[2] + b0.z, 0.f) * d; v[3] = fmaxf(v[3] + b0.w, 0.f) * d;
        v[4] = fmaxf(v[4] + b1.x, 0.f) * d; v[5] = fmaxf(v[5] + b1.y, 0.f) * d;
        v[6] = fmaxf(v[6] + b1.z, 0.f) * d; v[7] = fmaxf(v[7] + b1.w, 0.f) * d;
    }
    if (OUTH) {
        const __half2 h0 = __floats2half2_rn(v[0], v[1]);
        const __half2 h1 = __floats2half2_rn(v[2], v[3]);
        const __half2 h2 = __floats2half2_rn(v[4], v[5]);
        const __half2 h3 = __floats2half2_rn(v[6], v[7]);
        uint4 u;
        u.x = *(const unsigned int*)&h0; u.y = *(const unsigned int*)&h1;
        u.z = *(const unsigned int*)&h2; u.w = *(const unsigned int*)&h3;
        *(uint4*)((__half*)outv + (long)i * WD + q) = u;
    } else {
        float* out = (float*)outv;
        float4 v0, v1;
        v0.x = v[0]; v0.y = v[1]; v0.z = v[2]; v0.w = v[3];
        v1.x = v[4]; v1.y = v[5]; v1.z = v[6]; v1.w = v[7];
        *(float4*)&out[(long)i * WD + q] = v0;
        *(float4*)&out[(long)i * WD + q + 4] = v1;
    }
}

// ================= fp32 LDS-tiled GEMM (small layers L2-L5) =================
template<int FI, int FO, bool INB, bool OUTB, bool OUTRELU, bool OSC, bool OUTH>
__global__ __launch_bounds__(BLK) void gemm_k(const float* __restrict__ H, const float* __restrict__ Wm,
                                              const float* __restrict__ bin, const float* __restrict__ bout,
                                              const float* __restrict__ dinv, float* __restrict__ out, int n) {
    constexpr int COLT = FO / 4;
    constexpr int RTH  = BLK / COLT;
    constexpr int RPT  = (FO >= 64) ? 8 : 4;
    constexpr int ROWS = RTH * RPT;
    constexpr int KC   = (FI > 64) ? 64 : FI;
    constexpr int NKB  = FI / KC;

    __shared__ float Wl[KC * FO];
    __shared__ float Hl[ROWS * (KC + 1)];

    const int tid    = threadIdx.x;
    const int colIdx = tid % COLT;
    const int rowIdx = tid / COLT;
    const long rowBase = (long)blockIdx.x * ROWS;

    float4 acc[RPT];
#pragma unroll
    for (int i = 0; i < RPT; i++) acc[i] = make_float4(0.f, 0.f, 0.f, 0.f);

    for (int kb = 0; kb < NKB; kb++) {
        if (kb) __syncthreads();
        for (int f = tid * 4; f < KC * FO; f += BLK * 4) {
            const int kr = f / FO, c = f % FO;
            *(float4*)&Wl[kr * FO + c] = ld4(&Wm[(kb * KC + kr) * FO + c]);
        }
        for (int f = tid * 4; f < ROWS * KC; f += BLK * 4) {
            const int rr = f / KC, kk = f % KC;
            const long r = rowBase + rr;
            float4 v = make_float4(0.f, 0.f, 0.f, 0.f);
            if (r < n) v = ld4(&H[r * FI + kb * KC + kk]);
            if (INB) {
                float4 b4 = ld4(&bin[kb * KC + kk]);
                v.x = fmaxf(v.x + b4.x, 0.f); v.y = fmaxf(v.y + b4.y, 0.f);
                v.z = fmaxf(v.z + b4.z, 0.f); v.w = fmaxf(v.w + b4.w, 0.f);
            }
            float* dst = &Hl[rr * (KC + 1) + kk];
            dst[0] = v.x; dst[1] = v.y; dst[2] = v.z; dst[3] = v.w;
        }
        __syncthreads();
#pragma unroll 8
        for (int k = 0; k < KC; k++) {
            const float4 w4 = *(const float4*)&Wl[k * FO + 4 * colIdx];
#pragma unroll
            for (int i = 0; i < RPT; i++) {
                const float hv = Hl[(rowIdx * RPT + i) * (KC + 1) + k];
                acc[i].x = fmaf(hv, w4.x, acc[i].x);
                acc[i].y = fmaf(hv, w4.y, acc[i].y);
                acc[i].z = fmaf(hv, w4.z, acc[i].z);
                acc[i].w = fmaf(hv, w4.w, acc[i].w);
            }
        }
    }

    float4 bo = make_float4(0.f, 0.f, 0.f, 0.f);
    if (OUTB) bo = ld4(&bout[4 * colIdx]);
#pragma unroll
    for (int i = 0; i < RPT; i++) {
        const long r = rowBase + rowIdx * RPT + i;
        if (r < n) {
            float4 v = acc[i];
            if (OUTB) { v.x += bo.x; v.y += bo.y; v.z += bo.z; v.w += bo.w; }
            if (OUTRELU) {
                v.x = fmaxf(v.x, 0.f); v.y = fmaxf(v.y, 0.f);
                v.z = fmaxf(v.z, 0.f); v.w = fmaxf(v.w, 0.f);
            }
            if (OSC) {
                const float d = dinv[r];
                v.x *= d; v.y *= d; v.z *= d; v.w *= d;
            }
            if (OUTH) {
                const __half2 h01 = __floats2half2_rn(v.x, v.y);
                const __half2 h23 = __floats2half2_rn(v.z, v.w);
                uint2 u;
                u.x = *(const unsigned int*)&h01;
                u.y = *(const unsigned int*)&h23;
                *(uint2*)((__half*)out + r * FO + 4 * colIdx) = u;
            } else {
                *(float4*)&out[r * FO + 4 * colIdx] = v;
            }
        }
    }
}

// ================= W prep: fp32 KxFO -> fp16 FOxK, k-permuted per 32-block (one-shot) ======
// pk = (k & ~31) + 8*((k>>2)&3) + 4*((k>>4)&1) + (k&3): lane frag = one contiguous half8.
template<int K, int FO>
__global__ __launch_bounds__(BLK) void wprep_k(const float* __restrict__ Wm, _Float16* __restrict__ Wh) {
    const int f = (blockIdx.x * BLK + threadIdx.x) * 4;
    if (f >= K * FO) return;
    const int nn = f / K, k0 = f % K;          // k0 % 4 == 0
    const int blk = k0 & ~31, g = (k0 >> 2) & 3, h = (k0 >> 4) & 1;
    half4v w4;
#pragma unroll
    for (int c = 0; c < 4; c++) w4[c] = (_Float16)Wm[(k0 + c) * FO + nn];
    *(half4v*)&Wh[nn * K + blk + 8 * g + 4 * h] = w4;
}

// ================= MFMA fp16 GEMM (big layers). BM=64: 4 waves x 16 rows. ==================
// B from pre-permuted Wh (coalesced copy). Frag layout v_mfma_f32_16x16x32_f16 (R5-verified):
//   A/B: row|col = lane&15, k = (lane>>4)*4 + (j&3) + 16*(j>>2);  C/D: col=lane&15, row=(lane>>4)*4+reg.
template<int K, int FO, bool AH, bool OUTB, bool OUTRELU, bool OSC, bool OUTH>
__global__ __launch_bounds__(BLK) void mgemm_k(const void* __restrict__ Hv, const _Float16* __restrict__ Wh,
                                               const float* __restrict__ bout, const float* __restrict__ dinv,
                                               void* __restrict__ outv, int n) {
    constexpr int BM = 64;             // rows per block (4 waves x 16 rows)
    constexpr int KP = K + 8;          // padded row stride (halves); KP*2 is 16B-multiple
    constexpr int NT = FO / 16;        // 16-col tiles
    __shared__ _Float16 Al[BM * KP];
    __shared__ _Float16 Bl[FO * KP];

    const int tid = threadIdx.x;
    const long rowBase = (long)blockIdx.x * BM;

    // ---- stage B: coalesced 16B copies of pre-permuted Wh ----
    for (int f = tid * 8; f < K * FO; f += BLK * 8) {
        const int nn = f / K, k = f % K;       // k % 8 == 0
        *(uint4*)&Bl[nn * KP + k] = *(const uint4*)&Wh[f];
    }
    // ---- stage A (permute on the fly) ----
    if (AH) {
        const __half* Hp = (const __half*)Hv;
        for (int f = tid * 8; f < BM * K; f += BLK * 8) {
            const int rr = f / K, k0 = f % K;  // k0 % 8 == 0
            const long r = rowBase + rr;
            uint4 u = make_uint4(0u, 0u, 0u, 0u);
            if (r < n) u = *(const uint4*)&Hp[r * K + k0];
            const int blk = k0 & ~31, g0 = (k0 >> 2) & 3, h = (k0 >> 4) & 1;
            *(uint2*)&Al[rr * KP + blk + 8 * g0 + 4 * h] = make_uint2(u.x, u.y);
            *(uint2*)&Al[rr * KP + blk + 8 * (g0 + 1) + 4 * h] = make_uint2(u.z, u.w);
        }
    } else {
        const float* Hp = (const float*)Hv;
        for (int f = tid * 4; f < BM * K; f += BLK * 4) {
            const int rr = f / K, k0 = f % K;  // k0 % 4 == 0
            const long r = rowBase + rr;
            float4 v = make_float4(0.f, 0.f, 0.f, 0.f);
            if (r < n) v = ld4(&Hp[r * K + k0]);
            const int blk = k0 & ~31, g = (k0 >> 2) & 3, h = (k0 >> 4) & 1;
            half4v a4;
            a4[0] = (_Float16)v.x; a4[1] = (_Float16)v.y; a4[2] = (_Float16)v.z; a4[3] = (_Float16)v.w;
            *(half4v*)&Al[rr * KP + blk + 8 * g + 4 * h] = a4;
        }
    }
    __syncthreads();

    // ---- MFMA main loop: wave wv owns rows [wv*16, wv*16+16) x all FO cols ----
    const int wv = tid >> 6;
    const int lane = tid & 63;
    const int lr = lane & 15;
    const int lg = lane >> 4;
    const int wrow = wv * 16;

    const f32x4v vzero = {0.f, 0.f, 0.f, 0.f};
    f32x4v acc[NT];
#pragma unroll
    for (int t = 0; t < NT; t++) acc[t] = vzero;

#pragma unroll
    for (int ks = 0; ks < K / 32; ks++) {
        const int ko = ks * 32 + 8 * lg;
        const half8v a = *(const half8v*)&Al[(wrow + lr) * KP + ko];
#pragma unroll
        for (int nt = 0; nt < NT; nt++) {
            const half8v b = *(const half8v*)&Bl[(nt * 16 + lr) * KP + ko];
            acc[nt] = __builtin_amdgcn_mfma_f32_16x16x32_f16(a, b, acc[nt], 0, 0, 0);
        }
    }

    // ---- epilogue ----
    float bo[NT];
    if (OUTB) {
#pragma unroll
        for (int nt = 0; nt < NT; nt++) bo[nt] = bout[nt * 16 + lr];
    }
#pragma unroll
    for (int r = 0; r < 4; r++) {
        const long row = rowBase + wrow + lg * 4 + r;
        if (row < n) {
            const float d = OSC ? dinv[row] : 1.0f;
#pragma unroll
            for (int nt = 0; nt < NT; nt++) {
                float v = acc[nt][r];
                if (OUTB) v += bo[nt];
                if (OUTRELU) v = fmaxf(v, 0.f);
                if (OSC) v *= d;
                if (OUTH) ((__half*)outv)[row * FO + nt * 16 + lr] = __float2half_rn(v);
                else      ((float*)outv)[row * FO + nt * 16 + lr] = v;
            }
        }
    }
}

extern "C" void kernel_launch(void* const* d_in, const int* in_sizes, int n_in,
                              void* d_out, int out_size, void* d_ws, size_t ws_size,
                              hipStream_t stream)
{
    const float* x  = (const float*)d_in[0];
    const int*   ei = (const int*)d_in[1];
    const float* W1 = (const float*)d_in[3];  const float* b1 = (const float*)d_in[4];
    const float* W2 = (const float*)d_in[5];  const float* b2 = (const float*)d_in[6];
    const float* W3 = (const float*)d_in[7];  const float* b3 = (const float*)d_in[8];
    const float* W4 = (const float*)d_in[9];  const float* b4 = (const float*)d_in[10];
    const float* W5 = (const float*)d_in[11]; const float* b5 = (const float*)d_in[12];
    const float* W6 = (const float*)d_in[13]; const float* b6 = (const float*)d_in[14];
    const float* Wf = (const float*)d_in[15]; const float* bf = (const float*)d_in[16];

    const int n = in_sizes[0] / 128;
    const int E = in_sizes[1] / 2;
    const int* rows = ei;       // source j
    const int* cols = ei + E;   // target i

    // workspace layout — total (n + E + n + 128n + 128n)*4 = 116,000,000 B (proven safe).
    int*   P    = (int*)d_ws;                        // n ints
    int*   srow = P + n;                             // E ints (16B-aligned for n%4==0)
    float* dinv = (float*)(srow + E);                // n floats
    float* bufA = dinv + n;                          // n*128 floats
    float* bufB = bufA + (size_t)n * 128;            // n*128 floats
    // pre-layer aliases (dead before first use of bufA/bufB by the layer pipeline):
    int*   pairs = (int*)bufA;                       // E packed ints = 12.8MB (1.6MB/XCD: L2-resident)
    int*   hist  = (int*)bufB;                       // MAXNB*GPART ints = 1.64MB
    int*   bstart= hist + MAXNB * GPART;             // nb+1 ints (<= 1024+1)
    int*   tot   = bstart + 1032;                    // nb ints
    // persistent fp16 pre-permuted weights: bufB bytes [25.6MB, 25.6MB+64KB).
    // Every layer use of bufB is <= n*64 floats (= n*128 halves) = bytes [0, 25.6MB) -> no overlap.
    _Float16* Wh1 = (_Float16*)(bufB + (size_t)n * 64);  // 128*64
    _Float16* Wh6 = Wh1 + 128 * 64;                      // 64*128
    _Float16* Whf = Wh6 + 64 * 128;                      // 128*128

    auto cdiv = [](long a, long b) { return (unsigned)((a + b - 1) / b); };
    const int nb = (n + (1 << NBSHIFT) - 1) >> NBSHIFT;

    // --- one-shot W prep (touches only the Wh hole + weights) ---
    wprep_k<128, 64><<<cdiv(128 * 64 / 4, BLK), BLK, 0, stream>>>(W1, Wh1);
    wprep_k<64, 128><<<cdiv(64 * 128 / 4, BLK), BLK, 0, stream>>>(W6, Wh6);
    wprep_k<128, 128><<<cdiv(128 * 128 / 4, BLK), BLK, 0, stream>>>(Wf, Whf);

    // --- CSR build (atomic-free radix partition, 128-node buckets, packed 4B edges) ---
    p1_hist_k<<<GPART, BLK, 0, stream>>>(cols, hist, E, nb);
    p2a_tot_k<<<nb, 256, 0, stream>>>(hist, tot);
    p2a_scan_k<<<1, 256, 0, stream>>>(tot, bstart, nb, E);
    p2b_k<<<nb, 256, 0, stream>>>(hist, bstart);
    p3_part_k<<<GPART, BLK, 0, stream>>>(rows, cols, hist, pairs, E, nb);
    p4_fill_k<<<nb, BLK, 0, stream>>>(pairs, bstart, P, dinv, srow, n);

    // --- layers (all gather tables fp16; big GEMMs fp16-MFMA with fp32 accumulate) ---
    // L1 (MFMA): t1' = (x@W1)*dinv [fp16] ; a1 = gather_h(t1') -> fp32  [deferred: +b1, relu]
    mgemm_k<128, 64, false, false, false, true, true><<<cdiv(n, 64), BLK, 0, stream>>>(x, Wh1, nullptr, dinv, bufA, n);
    gatherh_k<64, false, false><<<cdiv((long)n * 8, BLK), BLK, 0, stream>>>((const __half*)bufA, P, srow, dinv, nullptr, bufB, n, E);

    // L2: t2' = (relu(a1+b1)@W2)*dinv [fp16] ; a2 = gather_h -> fp32    [deferred: +b2, relu]
    gemm_k<64, 32, true, false, false, true, true><<<cdiv(n, 128), BLK, 0, stream>>>(bufB, W2, b1, nullptr, dinv, bufA, n);
    gatherh_k<32, false, false><<<cdiv((long)n * 4, BLK), BLK, 0, stream>>>((const __half*)bufA, P, srow, dinv, nullptr, bufB, n, E);

    // L3: t3' = (relu(a2+b2)@W3)*dinv [fp16] ; gather w/ fused epilogue -> t4' = relu(a3+b3)*dinv [fp16]
    gemm_k<32, 16, true, false, false, true, true><<<cdiv(n, 256), BLK, 0, stream>>>(bufB, W3, b2, nullptr, dinv, bufA, n);
    gatherh_k<16, true, true><<<cdiv((long)n * 2, BLK), BLK, 0, stream>>>((const __half*)bufA, P, srow, dinv, b3, bufB, n, E);

    // L4: a4 = gather_h(t4') -> fp32 ; h4' = relu(a4@W4+b4)*dinv [fp16]
    gatherh_k<16, false, false><<<cdiv((long)n * 2, BLK), BLK, 0, stream>>>((const __half*)bufB, P, srow, dinv, nullptr, bufA, n, E);
    gemm_k<16, 32, false, true, true, true, true><<<cdiv(n, 128), BLK, 0, stream>>>(bufA, W4, nullptr, b4, dinv, bufB, n);

    // L5: a5 = gather_h(h4') -> fp32 ; h5' = relu(a5@W5+b5)*dinv [fp16]
    gatherh_k<32, false, false><<<cdiv((long)n * 4, BLK), BLK, 0, stream>>>((const __half*)bufB, P, srow, dinv, nullptr, bufA, n, E);
    gemm_k<32, 64, false, true, true, true, true><<<cdiv(n, 128), BLK, 0, stream>>>(bufA, W5, nullptr, b5, dinv, bufB, n);

    // L6: a6 = gather_h(h5') -> fp16 ; (MFMA) h6 = relu(a6@W6+b6) [fp16]
    gatherh_k<64, false, true><<<cdiv((long)n * 8, BLK), BLK, 0, stream>>>((const __half*)bufB, P, srow, dinv, nullptr, bufA, n, E);
    mgemm_k<64, 128, true, true, true, false, true><<<cdiv(n, 64), BLK, 0, stream>>>(bufA, Wh6, b6, nullptr, bufB, n);

    // final (MFMA): out = h6 @ Wf + bf  [fp32 out]
    mgemm_k<128, 128, true, true, false, false, false><<<cdiv(n, 64), BLK, 0, stream>>>(bufB, Whf, bf, nullptr, d_out, n);
}

// Round 13
// 566.901 us; speedup vs baseline: 1.4588x; 1.0552x over previous
//
#include <hip/hip_runtime.h>
#include <hip/hip_fp16.h>

#define BLK 256
#define NBSHIFT 7     // 128 nodes per bucket -> nb ~= 782 blocks (3/CU) for p4
#define MAXNB 800     // supports n <= 102400
#define GPART 512     // partition blocks
#define CMAX 6400     // max edges per p3 block chunk (E <= 6400*512)
// packed edge: (local<<17)|row ; requires n < 131072 and NBSHIFT <= 7 (local < 128)

typedef _Float16 half4v __attribute__((ext_vector_type(4)));
typedef _Float16 half8v __attribute__((ext_vector_type(8)));
typedef float    f32x4v __attribute__((ext_vector_type(4)));

__device__ __forceinline__ float4 ld4(const float* p) { return *(const float4*)p; }

// ================= CSR build: atomic-free radix partition by col>>NBSHIFT =================
__global__ __launch_bounds__(BLK) void p1_hist_k(const int* __restrict__ cols, int* __restrict__ hist,
                                                 int E, int nb) {
    __shared__ int h[MAXNB];
    const int tid = threadIdx.x, g = blockIdx.x;
    for (int b = tid; b < nb; b += BLK) h[b] = 0;
    __syncthreads();
    const int chunk = (E + GPART - 1) / GPART;
    const int start = g * chunk, end = min(E, start + chunk);
    for (int e = start + tid; e < end; e += BLK) atomicAdd(&h[cols[e] >> NBSHIFT], 1);
    __syncthreads();
    for (int b = tid; b < nb; b += BLK) hist[b * GPART + g] = h[b];
}
// P2a-tot: per-bucket total over its GPART block-counts. grid = nb.
__global__ __launch_bounds__(256) void p2a_tot_k(const int* __restrict__ hist, int* __restrict__ tot) {
    __shared__ int s[256];
    const int b = blockIdx.x, t = threadIdx.x;
    s[t] = hist[b * GPART + t] + hist[b * GPART + 256 + t];
    __syncthreads();
    for (int o = 128; o > 0; o >>= 1) {
        if (t < o) s[t] += s[t + o];
        __syncthreads();
    }
    if (t == 0) tot[b] = s[0];
}
// P2a-scan: single-block exclusive scan over nb (<=1024) totals -> bstart[0..nb], bstart[nb]=E.
__global__ __launch_bounds__(256) void p2a_scan_k(const int* __restrict__ tot, int* __restrict__ bstart,
                                                  int nb, int E) {
    __shared__ int s[256];
    const int t = threadIdx.x;
    const int base = t * 4;
    int l0 = 0, l1 = 0, l2 = 0, l3 = 0;
    if (base < nb)     l0 = tot[base];
    if (base + 1 < nb) l1 = tot[base + 1];
    if (base + 2 < nb) l2 = tot[base + 2];
    if (base + 3 < nb) l3 = tot[base + 3];
    const int sum = l0 + l1 + l2 + l3;
    s[t] = sum;
    __syncthreads();
    for (int o = 1; o < 256; o <<= 1) {
        const int v = s[t] + ((t >= o) ? s[t - o] : 0);
        __syncthreads();
        s[t] = v;
        __syncthreads();
    }
    const int excl = s[t] - sum;
    if (base < nb)     bstart[base]     = excl;
    if (base + 1 < nb) bstart[base + 1] = excl + l0;
    if (base + 2 < nb) bstart[base + 2] = excl + l0 + l1;
    if (base + 3 < nb) bstart[base + 3] = excl + l0 + l1 + l2;
    if (t == 0) bstart[nb] = E;
}
// P2b: per-bucket exclusive scan over its GPART block-counts, +bstart -> absolute offsets (in place).
__global__ __launch_bounds__(256) void p2b_k(int* __restrict__ hist, const int* __restrict__ bstart) {
    __shared__ int s[GPART];
    const int b = blockIdx.x, t = threadIdx.x;
    const int v0 = hist[b * GPART + t], v1 = hist[b * GPART + 256 + t];
    s[t] = v0; s[256 + t] = v1;
    __syncthreads();
    for (int o = 1; o < GPART; o <<= 1) {
        const int a0 = s[t] + ((t >= o) ? s[t - o] : 0);
        const int a1 = s[256 + t] + ((256 + t >= o) ? s[256 + t - o] : 0);
        __syncthreads();
        s[t] = a0; s[256 + t] = a1;
        __syncthreads();
    }
    const int base = bstart[b];
    hist[b * GPART + t] = base + s[t] - v0;
    hist[b * GPART + 256 + t] = base + s[256 + t] - v1;
}
// P3: per-block LDS counting sort by bucket, then fully-coalesced write-out.
// gdst(i) = (ghist[b][g] - lstart[b]) + i  for i in this block's sorted order.
__global__ __launch_bounds__(BLK) void p3_part_k(const int* __restrict__ rows, const int* __restrict__ cols,
                                                 const int* __restrict__ hist, int* __restrict__ pairs,
                                                 int E, int nb) {
    __shared__ int h[MAXNB];              // counts -> lstart (exclusive, in place)
    __shared__ int tailp[MAXNB];
    __shared__ int delta[MAXNB];
    __shared__ int sorted[CMAX];
    __shared__ unsigned short bkt[CMAX];
    __shared__ int s[256];
    const int tid = threadIdx.x, g = blockIdx.x;
    for (int b = tid; b < nb; b += BLK) h[b] = 0;
    __syncthreads();
    const int chunk = (E + GPART - 1) / GPART;
    const int start = g * chunk, end = min(E, start + chunk);
    const int cnt = end - start;
    for (int e = start + tid; e < end; e += BLK) atomicAdd(&h[cols[e] >> NBSHIFT], 1);
    __syncthreads();
    // exclusive scan of h[0..nb) (4 contiguous per thread; nb <= 1024)
    {
        const int base = tid * 4;
        int l0 = 0, l1 = 0, l2 = 0, l3 = 0;
        if (base < nb)     l0 = h[base];
        if (base + 1 < nb) l1 = h[base + 1];
        if (base + 2 < nb) l2 = h[base + 2];
        if (base + 3 < nb) l3 = h[base + 3];
        const int sum = l0 + l1 + l2 + l3;
        s[tid] = sum;
        __syncthreads();
        for (int o = 1; o < 256; o <<= 1) {
            const int v = s[tid] + ((tid >= o) ? s[tid - o] : 0);
            __syncthreads();
            s[tid] = v;
            __syncthreads();
        }
        const int excl = s[tid] - sum;
        if (base < nb)     h[base]     = excl;
        if (base + 1 < nb) h[base + 1] = excl + l0;
        if (base + 2 < nb) h[base + 2] = excl + l0 + l1;
        if (base + 3 < nb) h[base + 3] = excl + l0 + l1 + l2;
    }
    __syncthreads();
    for (int b = tid; b < nb; b += BLK) {
        const int ls = h[b];
        tailp[b] = ls;
        delta[b] = hist[b * GPART + g] - ls;
    }
    __syncthreads();
    // scatter into LDS (bucket-ordered)
    for (int e = start + tid; e < end; e += BLK) {
        const int r = rows[e], c = cols[e];
        const int b = c >> NBSHIFT;
        const int lpos = atomicAdd(&tailp[b], 1);
        sorted[lpos] = ((c & ((1 << NBSHIFT) - 1)) << 17) | r;
        bkt[lpos] = (unsigned short)b;
    }
    __syncthreads();
    // coalesced write-out
    for (int i = tid; i < cnt; i += BLK) {
        pairs[delta[bkt[i]] + i] = sorted[i];
    }
}
__global__ __launch_bounds__(BLK) void p4_fill_k(const int* __restrict__ pairs, const int* __restrict__ bstart,
                                                 int* __restrict__ P, float* __restrict__ dinv,
                                                 int* __restrict__ srow, int n) {
    constexpr int NN = 1 << NBSHIFT;
    __shared__ int dh[NN];
    __shared__ int tl[NN];
    const int b = blockIdx.x, t = threadIdx.x;
    const int base = b << NBSHIFT;
    const int nnod = min(NN, n - base);
    const int lo = bstart[b], hi = bstart[b + 1];
    if (t < NN) dh[t] = 0;
    __syncthreads();
    for (int e = lo + t; e < hi; e += BLK) atomicAdd(&dh[((unsigned)pairs[e]) >> 17], 1);
    __syncthreads();
    const int v0 = (t < NN) ? dh[t] : 0;
    if (t < NN) tl[t] = v0;
    __syncthreads();
    for (int o = 1; o < NN; o <<= 1) {
        int a0 = 0;
        if (t < NN) a0 = tl[t] + ((t >= o) ? tl[t - o] : 0);
        __syncthreads();
        if (t < NN) tl[t] = a0;
        __syncthreads();
    }
    const int s0 = lo + ((t < NN) ? tl[t] : 0) - v0;   // exclusive start of node base+t
    __syncthreads();
    if (t < NN) tl[t] = s0;
    if (t < nnod) { P[base + t] = s0; dinv[base + t] = rsqrtf((float)v0 + 1.0f); }
    __syncthreads();
    for (int e = lo + t; e < hi; e += BLK) {
        const int pv = pairs[e];
        const int pos = atomicAdd(&tl[((unsigned)pv) >> 17], 1);
        srow[pos] = pv & 0x1FFFF;
    }
}

// ================= fp16-input gather: rows of Tp stored as __half ==================
__device__ __forceinline__ void addh(float2 A[4], const __half* p) {
    const float4 raw = ld4((const float*)p);
    const __half2* h = (const __half2*)&raw;
    const float2 f0 = __half22float2(h[0]);
    const float2 f1 = __half22float2(h[1]);
    const float2 f2 = __half22float2(h[2]);
    const float2 f3 = __half22float2(h[3]);
    A[0].x += f0.x; A[0].y += f0.y;
    A[1].x += f1.x; A[1].y += f1.y;
    A[2].x += f2.x; A[2].y += f2.y;
    A[3].x += f3.x; A[3].y += f3.y;
}

template<int WD, bool PRE, bool OUTH>
__global__ __launch_bounds__(BLK) void gatherh_k(const __half* __restrict__ Tp, const int* __restrict__ P,
                                                 const int* __restrict__ srow, const float* __restrict__ dinv,
                                                 const float* __restrict__ bin, void* __restrict__ outv,
                                                 int n, int E) {
    constexpr int LPN = WD / 8;   // lanes per node
    const long gid = (long)blockIdx.x * BLK + threadIdx.x;
    const int i = (int)(gid / LPN);
    if (i >= n) return;
    const int q = (int)(gid % LPN) * 8;
    const int start = P[i];
    const int end = (i + 1 < n) ? P[i + 1] : E;
    const float d = dinv[i];
    const __half* __restrict__ Tq = Tp + q;
    float2 A0[4], A1[4], A2[4], A3[4];
    {   // self-loop
        const float4 raw = ld4((const float*)(Tq + (long)i * WD));
        const __half2* h = (const __half2*)&raw;
        A0[0] = __half22float2(h[0]); A0[1] = __half22float2(h[1]);
        A0[2] = __half22float2(h[2]); A0[3] = __half22float2(h[3]);
    }
#pragma unroll
    for (int k = 0; k < 4; k++) {
        A1[k] = make_float2(0.f, 0.f); A2[k] = make_float2(0.f, 0.f); A3[k] = make_float2(0.f, 0.f);
    }
    int e = start;
    const int ea = min(end, (start + 3) & ~3);   // align srow to int4
    for (; e < ea; e++) addh(A0, Tq + (long)srow[e] * WD);
    for (; e + 8 <= end; e += 8) {
        const int4 j0 = *(const int4*)&srow[e];
        const int4 j1 = *(const int4*)&srow[e + 4];
        addh(A0, Tq + (long)j0.x * WD); addh(A1, Tq + (long)j0.y * WD);
        addh(A2, Tq + (long)j0.z * WD); addh(A3, Tq + (long)j0.w * WD);
        addh(A0, Tq + (long)j1.x * WD); addh(A1, Tq + (long)j1.y * WD);
        addh(A2, Tq + (long)j1.z * WD); addh(A3, Tq + (long)j1.w * WD);
    }
    if (e + 4 <= end) {
        const int4 j0 = *(const int4*)&srow[e];
        addh(A0, Tq + (long)j0.x * WD); addh(A1, Tq + (long)j0.y * WD);
        addh(A2, Tq + (long)j0.z * WD); addh(A3, Tq + (long)j0.w * WD);
        e += 4;
    }
    for (; e < end; e++) addh(A0, Tq + (long)srow[e] * WD);
#pragma unroll
    for (int k = 0; k < 4; k++) {
        A0[k].x += A1[k].x + A2[k].x + A3[k].x;
        A0[k].y += A1[k].y + A2[k].y + A3[k].y;
    }
    float v[8];
    v[0] = d * A0[0].x; v[1] = d * A0[0].y; v[2] = d * A0[1].x; v[3] = d * A0[1].y;
    v[4] = d * A0[2].x; v[5] = d * A0[2].y; v[6] = d * A0[3].x; v[7] = d * A0[3].y;
    if (PRE) {
        const float4 b0 = ld4(&bin[q]);
        const float4 b1 = ld4(&bin[q + 4]);
        v[0] = fmaxf(v[0] + b0.x, 0.f) * d; v[1] = fmaxf(v[1] + b0.y, 0.f) * d;
        v[2] = fmaxf(v[2] + b0.z, 0.f) * d; v[3] = fmaxf(v[3] + b0.w, 0.f) * d;
        v[4] = fmaxf(v[4] + b1.x, 0.f) * d; v[5] = fmaxf(v[5] + b1.y, 0.f) * d;
        v[6] = fmaxf(v[6] + b1.z, 0.f) * d; v[7] = fmaxf(v[7] + b1.w, 0.f) * d;
    }
    if (OUTH) {
        const __half2 h0 = __floats2half2_rn(v[0], v[1]);
        const __half2 h1 = __floats2half2_rn(v[2], v[3]);
        const __half2 h2 = __floats2half2_rn(v[4], v[5]);
        const __half2 h3 = __floats2half2_rn(v[6], v[7]);
        uint4 u;
        u.x = *(const unsigned int*)&h0; u.y = *(const unsigned int*)&h1;
        u.z = *(const unsigned int*)&h2; u.w = *(const unsigned int*)&h3;
        *(uint4*)((__half*)outv + (long)i * WD + q) = u;
    } else {
        float* out = (float*)outv;
        float4 v0, v1;
        v0.x = v[0]; v0.y = v[1]; v0.z = v[2]; v0.w = v[3];
        v1.x = v[4]; v1.y = v[5]; v1.z = v[6]; v1.w = v[7];
        *(float4*)&out[(long)i * WD + q] = v0;
        *(float4*)&out[(long)i * WD + q + 4] = v1;
    }
}

// ================= fp32 LDS-tiled GEMM (small layers L2-L5) =================
template<int FI, int FO, bool INB, bool OUTB, bool OUTRELU, bool OSC, bool OUTH>
__global__ __launch_bounds__(BLK) void gemm_k(const float* __restrict__ H, const float* __restrict__ Wm,
                                              const float* __restrict__ bin, const float* __restrict__ bout,
                                              const float* __restrict__ dinv, float* __restrict__ out, int n) {
    constexpr int COLT = FO / 4;
    constexpr int RTH  = BLK / COLT;
    constexpr int RPT  = (FO >= 64) ? 8 : 4;
    constexpr int ROWS = RTH * RPT;
    constexpr int KC   = (FI > 64) ? 64 : FI;
    constexpr int NKB  = FI / KC;

    __shared__ float Wl[KC * FO];
    __shared__ float Hl[ROWS * (KC + 1)];

    const int tid    = threadIdx.x;
    const int colIdx = tid % COLT;
    const int rowIdx = tid / COLT;
    const long rowBase = (long)blockIdx.x * ROWS;

    float4 acc[RPT];
#pragma unroll
    for (int i = 0; i < RPT; i++) acc[i] = make_float4(0.f, 0.f, 0.f, 0.f);

    for (int kb = 0; kb < NKB; kb++) {
        if (kb) __syncthreads();
        for (int f = tid * 4; f < KC * FO; f += BLK * 4) {
            const int kr = f / FO, c = f % FO;
            *(float4*)&Wl[kr * FO + c] = ld4(&Wm[(kb * KC + kr) * FO + c]);
        }
        for (int f = tid * 4; f < ROWS * KC; f += BLK * 4) {
            const int rr = f / KC, kk = f % KC;
            const long r = rowBase + rr;
            float4 v = make_float4(0.f, 0.f, 0.f, 0.f);
            if (r < n) v = ld4(&H[r * FI + kb * KC + kk]);
            if (INB) {
                float4 b4 = ld4(&bin[kb * KC + kk]);
                v.x = fmaxf(v.x + b4.x, 0.f); v.y = fmaxf(v.y + b4.y, 0.f);
                v.z = fmaxf(v.z + b4.z, 0.f); v.w = fmaxf(v.w + b4.w, 0.f);
            }
            float* dst = &Hl[rr * (KC + 1) + kk];
            dst[0] = v.x; dst[1] = v.y; dst[2] = v.z; dst[3] = v.w;
        }
        __syncthreads();
#pragma unroll 8
        for (int k = 0; k < KC; k++) {
            const float4 w4 = *(const float4*)&Wl[k * FO + 4 * colIdx];
#pragma unroll
            for (int i = 0; i < RPT; i++) {
                const float hv = Hl[(rowIdx * RPT + i) * (KC + 1) + k];
                acc[i].x = fmaf(hv, w4.x, acc[i].x);
                acc[i].y = fmaf(hv, w4.y, acc[i].y);
                acc[i].z = fmaf(hv, w4.z, acc[i].z);
                acc[i].w = fmaf(hv, w4.w, acc[i].w);
            }
        }
    }

    float4 bo = make_float4(0.f, 0.f, 0.f, 0.f);
    if (OUTB) bo = ld4(&bout[4 * colIdx]);
#pragma unroll
    for (int i = 0; i < RPT; i++) {
        const long r = rowBase + rowIdx * RPT + i;
        if (r < n) {
            float4 v = acc[i];
            if (OUTB) { v.x += bo.x; v.y += bo.y; v.z += bo.z; v.w += bo.w; }
            if (OUTRELU) {
                v.x = fmaxf(v.x, 0.f); v.y = fmaxf(v.y, 0.f);
                v.z = fmaxf(v.z, 0.f); v.w = fmaxf(v.w, 0.f);
            }
            if (OSC) {
                const float d = dinv[r];
                v.x *= d; v.y *= d; v.z *= d; v.w *= d;
            }
            if (OUTH) {
                const __half2 h01 = __floats2half2_rn(v.x, v.y);
                const __half2 h23 = __floats2half2_rn(v.z, v.w);
                uint2 u;
                u.x = *(const unsigned int*)&h01;
                u.y = *(const unsigned int*)&h23;
                *(uint2*)((__half*)out + r * FO + 4 * colIdx) = u;
            } else {
                *(float4*)&out[r * FO + 4 * colIdx] = v;
            }
        }
    }
}

// ================= W prep: fp32 KxFO -> fp16 FOxK, k-permuted per 32-block (one-shot) ======
// pk = (k & ~31) + 8*((k>>2)&3) + 4*((k>>4)&1) + (k&3): lane frag = one contiguous half8.
template<int K, int FO>
__global__ __launch_bounds__(BLK) void wprep_k(const float* __restrict__ Wm, _Float16* __restrict__ Wh) {
    const int f = (blockIdx.x * BLK + threadIdx.x) * 4;
    if (f >= K * FO) return;
    const int nn = f / K, k0 = f % K;          // k0 % 4 == 0
    const int blk = k0 & ~31, g = (k0 >> 2) & 3, h = (k0 >> 4) & 1;
    half4v w4;
#pragma unroll
    for (int c = 0; c < 4; c++) w4[c] = (_Float16)Wm[(k0 + c) * FO + nn];
    *(half4v*)&Wh[nn * K + blk + 8 * g + 4 * h] = w4;
}

// ================= MFMA fp16 GEMM (big layers). BM=64: 4 waves x 16 rows. ==================
// B from pre-permuted Wh (coalesced copy). Frag layout v_mfma_f32_16x16x32_f16 (R5-verified):
//   A/B: row|col = lane&15, k = (lane>>4)*4 + (j&3) + 16*(j>>2);  C/D: col=lane&15, row=(lane>>4)*4+reg.
template<int K, int FO, bool AH, bool OUTB, bool OUTRELU, bool OSC, bool OUTH>
__global__ __launch_bounds__(BLK) void mgemm_k(const void* __restrict__ Hv, const _Float16* __restrict__ Wh,
                                               const float* __restrict__ bout, const float* __restrict__ dinv,
                                               void* __restrict__ outv, int n) {
    constexpr int BM = 64;             // rows per block (4 waves x 16 rows)
    constexpr int KP = K + 8;          // padded row stride (halves); KP*2 is 16B-multiple
    constexpr int NT = FO / 16;        // 16-col tiles
    __shared__ _Float16 Al[BM * KP];
    __shared__ _Float16 Bl[FO * KP];

    const int tid = threadIdx.x;
    const long rowBase = (long)blockIdx.x * BM;

    // ---- stage B: coalesced 16B copies of pre-permuted Wh ----
    for (int f = tid * 8; f < K * FO; f += BLK * 8) {
        const int nn = f / K, k = f % K;       // k % 8 == 0
        *(uint4*)&Bl[nn * KP + k] = *(const uint4*)&Wh[f];
    }
    // ---- stage A (permute on the fly) ----
    if (AH) {
        const __half* Hp = (const __half*)Hv;
        for (int f = tid * 8; f < BM * K; f += BLK * 8) {
            const int rr = f / K, k0 = f % K;  // k0 % 8 == 0
            const long r = rowBase + rr;
            uint4 u = make_uint4(0u, 0u, 0u, 0u);
            if (r < n) u = *(const uint4*)&Hp[r * K + k0];
            const int blk = k0 & ~31, g0 = (k0 >> 2) & 3, h = (k0 >> 4) & 1;
            *(uint2*)&Al[rr * KP + blk + 8 * g0 + 4 * h] = make_uint2(u.x, u.y);
            *(uint2*)&Al[rr * KP + blk + 8 * (g0 + 1) + 4 * h] = make_uint2(u.z, u.w);
        }
    } else {
        const float* Hp = (const float*)Hv;
        for (int f = tid * 4; f < BM * K; f += BLK * 4) {
            const int rr = f / K, k0 = f % K;  // k0 % 4 == 0
            const long r = rowBase + rr;
            float4 v = make_float4(0.f, 0.f, 0.f, 0.f);
            if (r < n) v = ld4(&Hp[r * K + k0]);
            const int blk = k0 & ~31, g = (k0 >> 2) & 3, h = (k0 >> 4) & 1;
            half4v a4;
            a4[0] = (_Float16)v.x; a4[1] = (_Float16)v.y; a4[2] = (_Float16)v.z; a4[3] = (_Float16)v.w;
            *(half4v*)&Al[rr * KP + blk + 8 * g + 4 * h] = a4;
        }
    }
    __syncthreads();

    // ---- MFMA main loop: wave wv owns rows [wv*16, wv*16+16) x all FO cols ----
    const int wv = tid >> 6;
    const int lane = tid & 63;
    const int lr = lane & 15;
    const int lg = lane >> 4;
    const int wrow = wv * 16;

    const f32x4v vzero = {0.f, 0.f, 0.f, 0.f};
    f32x4v acc[NT];
#pragma unroll
    for (int t = 0; t < NT; t++) acc[t] = vzero;

#pragma unroll
    for (int ks = 0; ks < K / 32; ks++) {
        const int ko = ks * 32 + 8 * lg;
        const half8v a = *(const half8v*)&Al[(wrow + lr) * KP + ko];
#pragma unroll
        for (int nt = 0; nt < NT; nt++) {
            const half8v b = *(const half8v*)&Bl[(nt * 16 + lr) * KP + ko];
            acc[nt] = __builtin_amdgcn_mfma_f32_16x16x32_f16(a, b, acc[nt], 0, 0, 0);
        }
    }

    // ---- epilogue ----
    float bo[NT];
    if (OUTB) {
#pragma unroll
        for (int nt = 0; nt < NT; nt++) bo[nt] = bout[nt * 16 + lr];
    }
#pragma unroll
    for (int r = 0; r < 4; r++) {
        const long row = rowBase + wrow + lg * 4 + r;
        if (row < n) {
            const float d = OSC ? dinv[row] : 1.0f;
#pragma unroll
            for (int nt = 0; nt < NT; nt++) {
                float v = acc[nt][r];
                if (OUTB) v += bo[nt];
                if (OUTRELU) v = fmaxf(v, 0.f);
                if (OSC) v *= d;
                if (OUTH) ((__half*)outv)[row * FO + nt * 16 + lr] = __float2half_rn(v);
                else      ((float*)outv)[row * FO + nt * 16 + lr] = v;
            }
        }
    }
}

extern "C" void kernel_launch(void* const* d_in, const int* in_sizes, int n_in,
                              void* d_out, int out_size, void* d_ws, size_t ws_size,
                              hipStream_t stream)
{
    const float* x  = (const float*)d_in[0];
    const int*   ei = (const int*)d_in[1];
    const float* W1 = (const float*)d_in[3];  const float* b1 = (const float*)d_in[4];
    const float* W2 = (const float*)d_in[5];  const float* b2 = (const float*)d_in[6];
    const float* W3 = (const float*)d_in[7];  const float* b3 = (const float*)d_in[8];
    const float* W4 = (const float*)d_in[9];  const float* b4 = (const float*)d_in[10];
    const float* W5 = (const float*)d_in[11]; const float* b5 = (const float*)d_in[12];
    const float* W6 = (const float*)d_in[13]; const float* b6 = (const float*)d_in[14];
    const float* Wf = (const float*)d_in[15]; const float* bf = (const float*)d_in[16];

    const int n = in_sizes[0] / 128;
    const int E = in_sizes[1] / 2;
    const int* rows = ei;       // source j
    const int* cols = ei + E;   // target i

    // workspace layout — total (n + E + n + 128n + 128n)*4 = 116,000,000 B (proven safe).
    int*   P    = (int*)d_ws;                        // n ints
    int*   srow = P + n;                             // E ints (16B-aligned for n%4==0)
    float* dinv = (float*)(srow + E);                // n floats
    float* bufA = dinv + n;                          // n*128 floats
    float* bufB = bufA + (size_t)n * 128;            // n*128 floats
    // pre-layer aliases (dead before first use of bufA/bufB by the layer pipeline):
    int*   pairs = (int*)bufA;                       // E packed ints = 12.8MB
    int*   hist  = (int*)bufB;                       // MAXNB*GPART ints = 1.64MB
    int*   bstart= hist + MAXNB * GPART;             // nb+1 ints (<= 1024+1)
    int*   tot   = bstart + 1032;                    // nb ints
    // persistent fp16 pre-permuted weights: bufB bytes [25.6MB, 25.6MB+64KB).
    // Every layer use of bufB is <= n*64 floats (= n*128 halves) = bytes [0, 25.6MB) -> no overlap.
    _Float16* Wh1 = (_Float16*)(bufB + (size_t)n * 64);  // 128*64
    _Float16* Wh6 = Wh1 + 128 * 64;                      // 64*128
    _Float16* Whf = Wh6 + 64 * 128;                      // 128*128

    auto cdiv = [](long a, long b) { return (unsigned)((a + b - 1) / b); };
    const int nb = (n + (1 << NBSHIFT) - 1) >> NBSHIFT;

    // --- one-shot W prep (touches only the Wh hole + weights) ---
    wprep_k<128, 64><<<cdiv(128 * 64 / 4, BLK), BLK, 0, stream>>>(W1, Wh1);
    wprep_k<64, 128><<<cdiv(64 * 128 / 4, BLK), BLK, 0, stream>>>(W6, Wh6);
    wprep_k<128, 128><<<cdiv(128 * 128 / 4, BLK), BLK, 0, stream>>>(Wf, Whf);

    // --- CSR build (atomic-free radix partition, 128-node buckets, packed 4B edges) ---
    p1_hist_k<<<GPART, BLK, 0, stream>>>(cols, hist, E, nb);
    p2a_tot_k<<<nb, 256, 0, stream>>>(hist, tot);
    p2a_scan_k<<<1, 256, 0, stream>>>(tot, bstart, nb, E);
    p2b_k<<<nb, 256, 0, stream>>>(hist, bstart);
    p3_part_k<<<GPART, BLK, 0, stream>>>(rows, cols, hist, pairs, E, nb);
    p4_fill_k<<<nb, BLK, 0, stream>>>(pairs, bstart, P, dinv, srow, n);

    // --- layers (all gather tables fp16; big GEMMs fp16-MFMA with fp32 accumulate) ---
    // L1 (MFMA): t1' = (x@W1)*dinv [fp16] ; a1 = gather_h(t1') -> fp32  [deferred: +b1, relu]
    mgemm_k<128, 64, false, false, false, true, true><<<cdiv(n, 64), BLK, 0, stream>>>(x, Wh1, nullptr, dinv, bufA, n);
    gatherh_k<64, false, false><<<cdiv((long)n * 8, BLK), BLK, 0, stream>>>((const __half*)bufA, P, srow, dinv, nullptr, bufB, n, E);

    // L2: t2' = (relu(a1+b1)@W2)*dinv [fp16] ; a2 = gather_h -> fp32    [deferred: +b2, relu]
    gemm_k<64, 32, true, false, false, true, true><<<cdiv(n, 128), BLK, 0, stream>>>(bufB, W2, b1, nullptr, dinv, bufA, n);
    gatherh_k<32, false, false><<<cdiv((long)n * 4, BLK), BLK, 0, stream>>>((const __half*)bufA, P, srow, dinv, nullptr, bufB, n, E);

    // L3: t3' = (relu(a2+b2)@W3)*dinv [fp16] ; gather w/ fused epilogue -> t4' = relu(a3+b3)*dinv [fp16]
    gemm_k<32, 16, true, false, false, true, true><<<cdiv(n, 256), BLK, 0, stream>>>(bufB, W3, b2, nullptr, dinv, bufA, n);
    gatherh_k<16, true, true><<<cdiv((long)n * 2, BLK), BLK, 0, stream>>>((const __half*)bufA, P, srow, dinv, b3, bufB, n, E);

    // L4: a4 = gather_h(t4') -> fp32 ; h4' = relu(a4@W4+b4)*dinv [fp16]
    gatherh_k<16, false, false><<<cdiv((long)n * 2, BLK), BLK, 0, stream>>>((const __half*)bufB, P, srow, dinv, nullptr, bufA, n, E);
    gemm_k<16, 32, false, true, true, true, true><<<cdiv(n, 128), BLK, 0, stream>>>(bufA, W4, nullptr, b4, dinv, bufB, n);

    // L5: a5 = gather_h(h4') -> fp32 ; h5' = relu(a5@W5+b5)*dinv [fp16]
    gatherh_k<32, false, false><<<cdiv((long)n * 4, BLK), BLK, 0, stream>>>((const __half*)bufB, P, srow, dinv, nullptr, bufA, n, E);
    gemm_k<32, 64, false, true, true, true, true><<<cdiv(n, 128), BLK, 0, stream>>>(bufA, W5, nullptr, b5, dinv, bufB, n);

    // L6: a6 = gather_h(h5') -> fp16 ; (MFMA) h6 = relu(a6@W6+b6) [fp16]
    gatherh_k<64, false, true><<<cdiv((long)n * 8, BLK), BLK, 0, stream>>>((const __half*)bufB, P, srow, dinv, nullptr, bufA, n, E);
    mgemm_k<64, 128, true, true, true, false, true><<<cdiv(n, 64), BLK, 0, stream>>>(bufA, Wh6, b6, nullptr, bufB, n);

    // final (MFMA): out = h6 @ Wf + bf  [fp32 out]
    mgemm_k<128, 128, true, true, false, false, false><<<cdiv(n, 64), BLK, 0, stream>>>(bufB, Whf, bf, nullptr, d_out, n);
}

// Round 14
// 561.779 us; speedup vs baseline: 1.4721x; 1.0091x over previous
//
#include <hip/hip_runtime.h>
#include <hip/hip_fp16.h>

#define BLK 256
#define NBSHIFT 7     // 128 nodes per bucket -> nb ~= 782 blocks (3/CU) for p4
#define MAXNB 800     // supports n <= 102400
#define GPART 512     // partition blocks
#define CMAX 6400     // max edges per p3 block chunk (E <= 6400*512)
// packed edge: (local<<17)|row ; requires n < 131072 and NBSHIFT <= 7 (local < 128)

typedef _Float16 half4v __attribute__((ext_vector_type(4)));
typedef _Float16 half8v __attribute__((ext_vector_type(8)));
typedef float    f32x4v __attribute__((ext_vector_type(4)));

__device__ __forceinline__ float4 ld4(const float* p) { return *(const float4*)p; }

// ================= CSR build: atomic-free radix partition by col>>NBSHIFT =================
__global__ __launch_bounds__(BLK) void p1_hist_k(const int* __restrict__ cols, int* __restrict__ hist,
                                                 int E, int nb) {
    __shared__ int h[MAXNB];
    const int tid = threadIdx.x, g = blockIdx.x;
    for (int b = tid; b < nb; b += BLK) h[b] = 0;
    __syncthreads();
    const int chunk = (E + GPART - 1) / GPART;
    const int start = g * chunk, end = min(E, start + chunk);
    for (int e = start + tid; e < end; e += BLK) atomicAdd(&h[cols[e] >> NBSHIFT], 1);
    __syncthreads();
    for (int b = tid; b < nb; b += BLK) hist[b * GPART + g] = h[b];
}
// P2a-tot: per-bucket total over its GPART block-counts. grid = nb.
__global__ __launch_bounds__(256) void p2a_tot_k(const int* __restrict__ hist, int* __restrict__ tot) {
    __shared__ int s[256];
    const int b = blockIdx.x, t = threadIdx.x;
    s[t] = hist[b * GPART + t] + hist[b * GPART + 256 + t];
    __syncthreads();
    for (int o = 128; o > 0; o >>= 1) {
        if (t < o) s[t] += s[t + o];
        __syncthreads();
    }
    if (t == 0) tot[b] = s[0];
}
// P2a-scan: single-block exclusive scan over nb (<=1024) totals -> bstart[0..nb], bstart[nb]=E.
__global__ __launch_bounds__(256) void p2a_scan_k(const int* __restrict__ tot, int* __restrict__ bstart,
                                                  int nb, int E) {
    __shared__ int s[256];
    const int t = threadIdx.x;
    const int base = t * 4;
    int l0 = 0, l1 = 0, l2 = 0, l3 = 0;
    if (base < nb)     l0 = tot[base];
    if (base + 1 < nb) l1 = tot[base + 1];
    if (base + 2 < nb) l2 = tot[base + 2];
    if (base + 3 < nb) l3 = tot[base + 3];
    const int sum = l0 + l1 + l2 + l3;
    s[t] = sum;
    __syncthreads();
    for (int o = 1; o < 256; o <<= 1) {
        const int v = s[t] + ((t >= o) ? s[t - o] : 0);
        __syncthreads();
        s[t] = v;
        __syncthreads();
    }
    const int excl = s[t] - sum;
    if (base < nb)     bstart[base]     = excl;
    if (base + 1 < nb) bstart[base + 1] = excl + l0;
    if (base + 2 < nb) bstart[base + 2] = excl + l0 + l1;
    if (base + 3 < nb) bstart[base + 3] = excl + l0 + l1 + l2;
    if (t == 0) bstart[nb] = E;
}
// P2b: per-bucket exclusive scan over its GPART block-counts, +bstart -> absolute offsets (in place).
__global__ __launch_bounds__(256) void p2b_k(int* __restrict__ hist, const int* __restrict__ bstart) {
    __shared__ int s[GPART];
    const int b = blockIdx.x, t = threadIdx.x;
    const int v0 = hist[b * GPART + t], v1 = hist[b * GPART + 256 + t];
    s[t] = v0; s[256 + t] = v1;
    __syncthreads();
    for (int o = 1; o < GPART; o <<= 1) {
        const int a0 = s[t] + ((t >= o) ? s[t - o] : 0);
        const int a1 = s[256 + t] + ((256 + t >= o) ? s[256 + t - o] : 0);
        __syncthreads();
        s[t] = a0; s[256 + t] = a1;
        __syncthreads();
    }
    const int base = bstart[b];
    hist[b * GPART + t] = base + s[t] - v0;
    hist[b * GPART + 256 + t] = base + s[256 + t] - v1;
}
// P3: per-block LDS counting sort by bucket, then fully-coalesced write-out.
// gdst(i) = (ghist[b][g] - lstart[b]) + i  for i in this block's sorted order.
__global__ __launch_bounds__(BLK) void p3_part_k(const int* __restrict__ rows, const int* __restrict__ cols,
                                                 const int* __restrict__ hist, int* __restrict__ pairs,
                                                 int E, int nb) {
    __shared__ int h[MAXNB];              // counts -> lstart (exclusive, in place)
    __shared__ int tailp[MAXNB];
    __shared__ int delta[MAXNB];
    __shared__ int sorted[CMAX];
    __shared__ unsigned short bkt[CMAX];
    __shared__ int s[256];
    const int tid = threadIdx.x, g = blockIdx.x;
    for (int b = tid; b < nb; b += BLK) h[b] = 0;
    __syncthreads();
    const int chunk = (E + GPART - 1) / GPART;
    const int start = g * chunk, end = min(E, start + chunk);
    const int cnt = end - start;
    for (int e = start + tid; e < end; e += BLK) atomicAdd(&h[cols[e] >> NBSHIFT], 1);
    __syncthreads();
    // exclusive scan of h[0..nb) (4 contiguous per thread; nb <= 1024)
    {
        const int base = tid * 4;
        int l0 = 0, l1 = 0, l2 = 0, l3 = 0;
        if (base < nb)     l0 = h[base];
        if (base + 1 < nb) l1 = h[base + 1];
        if (base + 2 < nb) l2 = h[base + 2];
        if (base + 3 < nb) l3 = h[base + 3];
        const int sum = l0 + l1 + l2 + l3;
        s[tid] = sum;
        __syncthreads();
        for (int o = 1; o < 256; o <<= 1) {
            const int v = s[tid] + ((tid >= o) ? s[tid - o] : 0);
            __syncthreads();
            s[tid] = v;
            __syncthreads();
        }
        const int excl = s[tid] - sum;
        if (base < nb)     h[base]     = excl;
        if (base + 1 < nb) h[base + 1] = excl + l0;
        if (base + 2 < nb) h[base + 2] = excl + l0 + l1;
        if (base + 3 < nb) h[base + 3] = excl + l0 + l1 + l2;
    }
    __syncthreads();
    for (int b = tid; b < nb; b += BLK) {
        const int ls = h[b];
        tailp[b] = ls;
        delta[b] = hist[b * GPART + g] - ls;
    }
    __syncthreads();
    // scatter into LDS (bucket-ordered)
    for (int e = start + tid; e < end; e += BLK) {
        const int r = rows[e], c = cols[e];
        const int b = c >> NBSHIFT;
        const int lpos = atomicAdd(&tailp[b], 1);
        sorted[lpos] = ((c & ((1 << NBSHIFT) - 1)) << 17) | r;
        bkt[lpos] = (unsigned short)b;
    }
    __syncthreads();
    // coalesced write-out
    for (int i = tid; i < cnt; i += BLK) {
        pairs[delta[bkt[i]] + i] = sorted[i];
    }
}
__global__ __launch_bounds__(BLK) void p4_fill_k(const int* __restrict__ pairs, const int* __restrict__ bstart,
                                                 int* __restrict__ P, float* __restrict__ dinv,
                                                 int* __restrict__ srow, int n) {
    constexpr int NN = 1 << NBSHIFT;
    __shared__ int dh[NN];
    __shared__ int tl[NN];
    const int b = blockIdx.x, t = threadIdx.x;
    const int base = b << NBSHIFT;
    const int nnod = min(NN, n - base);
    const int lo = bstart[b], hi = bstart[b + 1];
    if (t < NN) dh[t] = 0;
    __syncthreads();
    for (int e = lo + t; e < hi; e += BLK) atomicAdd(&dh[((unsigned)pairs[e]) >> 17], 1);
    __syncthreads();
    const int v0 = (t < NN) ? dh[t] : 0;
    if (t < NN) tl[t] = v0;
    __syncthreads();
    for (int o = 1; o < NN; o <<= 1) {
        int a0 = 0;
        if (t < NN) a0 = tl[t] + ((t >= o) ? tl[t - o] : 0);
        __syncthreads();
        if (t < NN) tl[t] = a0;
        __syncthreads();
    }
    const int s0 = lo + ((t < NN) ? tl[t] : 0) - v0;   // exclusive start of node base+t
    __syncthreads();
    if (t < NN) tl[t] = s0;
    if (t < nnod) { P[base + t] = s0; dinv[base + t] = rsqrtf((float)v0 + 1.0f); }
    __syncthreads();
    for (int e = lo + t; e < hi; e += BLK) {
        const int pv = pairs[e];
        const int pos = atomicAdd(&tl[((unsigned)pv) >> 17], 1);
        srow[pos] = pv & 0x1FFFF;
    }
}

// ================= fp16-input gather: rows of Tp stored as __half ==================
__device__ __forceinline__ void addh(float2 A[4], const __half* p) {
    const float4 raw = ld4((const float*)p);
    const __half2* h = (const __half2*)&raw;
    const float2 f0 = __half22float2(h[0]);
    const float2 f1 = __half22float2(h[1]);
    const float2 f2 = __half22float2(h[2]);
    const float2 f3 = __half22float2(h[3]);
    A[0].x += f0.x; A[0].y += f0.y;
    A[1].x += f1.x; A[1].y += f1.y;
    A[2].x += f2.x; A[2].y += f2.y;
    A[3].x += f3.x; A[3].y += f3.y;
}

template<int WD, bool PRE, bool OUTH>
__global__ __launch_bounds__(BLK) void gatherh_k(const __half* __restrict__ Tp, const int* __restrict__ P,
                                                 const int* __restrict__ srow, const float* __restrict__ dinv,
                                                 const float* __restrict__ bin, void* __restrict__ outv,
                                                 int n, int E) {
    constexpr int LPN = WD / 8;   // lanes per node
    const long gid = (long)blockIdx.x * BLK + threadIdx.x;
    const int i = (int)(gid / LPN);
    if (i >= n) return;
    const int q = (int)(gid % LPN) * 8;
    const int start = P[i];
    const int end = (i + 1 < n) ? P[i + 1] : E;
    const float d = dinv[i];
    const __half* __restrict__ Tq = Tp + q;
    float2 A0[4], A1[4], A2[4], A3[4];
    {   // self-loop
        const float4 raw = ld4((const float*)(Tq + (long)i * WD));
        const __half2* h = (const __half2*)&raw;
        A0[0] = __half22float2(h[0]); A0[1] = __half22float2(h[1]);
        A0[2] = __half22float2(h[2]); A0[3] = __half22float2(h[3]);
    }
#pragma unroll
    for (int k = 0; k < 4; k++) {
        A1[k] = make_float2(0.f, 0.f); A2[k] = make_float2(0.f, 0.f); A3[k] = make_float2(0.f, 0.f);
    }
    int e = start;
    const int ea = min(end, (start + 3) & ~3);   // align srow to int4
    for (; e < ea; e++) addh(A0, Tq + (long)srow[e] * WD);
    for (; e + 8 <= end; e += 8) {
        const int4 j0 = *(const int4*)&srow[e];
        const int4 j1 = *(const int4*)&srow[e + 4];
        addh(A0, Tq + (long)j0.x * WD); addh(A1, Tq + (long)j0.y * WD);
        addh(A2, Tq + (long)j0.z * WD); addh(A3, Tq + (long)j0.w * WD);
        addh(A0, Tq + (long)j1.x * WD); addh(A1, Tq + (long)j1.y * WD);
        addh(A2, Tq + (long)j1.z * WD); addh(A3, Tq + (long)j1.w * WD);
    }
    if (e + 4 <= end) {
        const int4 j0 = *(const int4*)&srow[e];
        addh(A0, Tq + (long)j0.x * WD); addh(A1, Tq + (long)j0.y * WD);
        addh(A2, Tq + (long)j0.z * WD); addh(A3, Tq + (long)j0.w * WD);
        e += 4;
    }
    for (; e < end; e++) addh(A0, Tq + (long)srow[e] * WD);
#pragma unroll
    for (int k = 0; k < 4; k++) {
        A0[k].x += A1[k].x + A2[k].x + A3[k].x;
        A0[k].y += A1[k].y + A2[k].y + A3[k].y;
    }
    float v[8];
    v[0] = d * A0[0].x; v[1] = d * A0[0].y; v[2] = d * A0[1].x; v[3] = d * A0[1].y;
    v[4] = d * A0[2].x; v[5] = d * A0[2].y; v[6] = d * A0[3].x; v[7] = d * A0[3].y;
    if (PRE) {
        const float4 b0 = ld4(&bin[q]);
        const float4 b1 = ld4(&bin[q + 4]);
        v[0] = fmaxf(v[0] + b0.x, 0.f) * d; v[1] = fmaxf(v[1] + b0.y, 0.f) * d;
        v[2] = fmaxf(v[2] + b0.z, 0.f) * d; v[3] = fmaxf(v[3] + b0.w, 0.f) * d;
        v[4] = fmaxf(v[4] + b1.x, 0.f) * d; v[5] = fmaxf(v[5] + b1.y, 0.f) * d;
        v[6] = fmaxf(v[6] + b1.z, 0.f) * d; v[7] = fmaxf(v[7] + b1.w, 0.f) * d;
    }
    if (OUTH) {
        const __half2 h0 = __floats2half2_rn(v[0], v[1]);
        const __half2 h1 = __floats2half2_rn(v[2], v[3]);
        const __half2 h2 = __floats2half2_rn(v[4], v[5]);
        const __half2 h3 = __floats2half2_rn(v[6], v[7]);
        uint4 u;
        u.x = *(const unsigned int*)&h0; u.y = *(const unsigned int*)&h1;
        u.z = *(const unsigned int*)&h2; u.w = *(const unsigned int*)&h3;
        *(uint4*)((__half*)outv + (long)i * WD + q) = u;
    } else {
        float* out = (float*)outv;
        float4 v0, v1;
        v0.x = v[0]; v0.y = v[1]; v0.z = v[2]; v0.w = v[3];
        v1.x = v[4]; v1.y = v[5]; v1.z = v[6]; v1.w = v[7];
        *(float4*)&out[(long)i * WD + q] = v0;
        *(float4*)&out[(long)i * WD + q + 4] = v1;
    }
}

// ================= LDS-tiled GEMM (small layers L2-L5) =================
// AH: input H is fp16 (8 halves/thread staged, converted to fp32 in LDS).
template<int FI, int FO, bool INB, bool OUTB, bool OUTRELU, bool OSC, bool OUTH, bool AH>
__global__ __launch_bounds__(BLK) void gemm_k(const void* __restrict__ Hv, const float* __restrict__ Wm,
                                              const float* __restrict__ bin, const float* __restrict__ bout,
                                              const float* __restrict__ dinv, float* __restrict__ out, int n) {
    constexpr int COLT = FO / 4;
    constexpr int RTH  = BLK / COLT;
    constexpr int RPT  = (FO >= 64) ? 8 : 4;
    constexpr int ROWS = RTH * RPT;
    constexpr int KC   = (FI > 64) ? 64 : FI;
    constexpr int NKB  = FI / KC;

    __shared__ float Wl[KC * FO];
    __shared__ float Hl[ROWS * (KC + 1)];

    const int tid    = threadIdx.x;
    const int colIdx = tid % COLT;
    const int rowIdx = tid / COLT;
    const long rowBase = (long)blockIdx.x * ROWS;

    float4 acc[RPT];
#pragma unroll
    for (int i = 0; i < RPT; i++) acc[i] = make_float4(0.f, 0.f, 0.f, 0.f);

    for (int kb = 0; kb < NKB; kb++) {
        if (kb) __syncthreads();
        for (int f = tid * 4; f < KC * FO; f += BLK * 4) {
            const int kr = f / FO, c = f % FO;
            *(float4*)&Wl[kr * FO + c] = ld4(&Wm[(kb * KC + kr) * FO + c]);
        }
        if (AH) {
            const __half* Hp = (const __half*)Hv;
            for (int f = tid * 8; f < ROWS * KC; f += BLK * 8) {
                const int rr = f / KC, kk = f % KC;
                const long r = rowBase + rr;
                uint4 u = make_uint4(0u, 0u, 0u, 0u);
                if (r < n) u = *(const uint4*)&Hp[r * FI + kb * KC + kk];
                const __half2* hh = (const __half2*)&u;
                float v[8];
#pragma unroll
                for (int j = 0; j < 4; j++) {
                    const float2 f2 = __half22float2(hh[j]);
                    v[2 * j] = f2.x; v[2 * j + 1] = f2.y;
                }
                if (INB) {
#pragma unroll
                    for (int j = 0; j < 8; j++) v[j] = fmaxf(v[j] + bin[kb * KC + kk + j], 0.f);
                }
                float* dst = &Hl[rr * (KC + 1) + kk];
#pragma unroll
                for (int j = 0; j < 8; j++) dst[j] = v[j];
            }
        } else {
            const float* Hp = (const float*)Hv;
            for (int f = tid * 4; f < ROWS * KC; f += BLK * 4) {
                const int rr = f / KC, kk = f % KC;
                const long r = rowBase + rr;
                float4 v = make_float4(0.f, 0.f, 0.f, 0.f);
                if (r < n) v = ld4(&Hp[r * FI + kb * KC + kk]);
                if (INB) {
                    float4 b4 = ld4(&bin[kb * KC + kk]);
                    v.x = fmaxf(v.x + b4.x, 0.f); v.y = fmaxf(v.y + b4.y, 0.f);
                    v.z = fmaxf(v.z + b4.z, 0.f); v.w = fmaxf(v.w + b4.w, 0.f);
                }
                float* dst = &Hl[rr * (KC + 1) + kk];
                dst[0] = v.x; dst[1] = v.y; dst[2] = v.z; dst[3] = v.w;
            }
        }
        __syncthreads();
#pragma unroll 8
        for (int k = 0; k < KC; k++) {
            const float4 w4 = *(const float4*)&Wl[k * FO + 4 * colIdx];
#pragma unroll
            for (int i = 0; i < RPT; i++) {
                const float hv = Hl[(rowIdx * RPT + i) * (KC + 1) + k];
                acc[i].x = fmaf(hv, w4.x, acc[i].x);
                acc[i].y = fmaf(hv, w4.y, acc[i].y);
                acc[i].z = fmaf(hv, w4.z, acc[i].z);
                acc[i].w = fmaf(hv, w4.w, acc[i].w);
            }
        }
    }

    float4 bo = make_float4(0.f, 0.f, 0.f, 0.f);
    if (OUTB) bo = ld4(&bout[4 * colIdx]);
#pragma unroll
    for (int i = 0; i < RPT; i++) {
        const long r = rowBase + rowIdx * RPT + i;
        if (r < n) {
            float4 v = acc[i];
            if (OUTB) { v.x += bo.x; v.y += bo.y; v.z += bo.z; v.w += bo.w; }
            if (OUTRELU) {
                v.x = fmaxf(v.x, 0.f); v.y = fmaxf(v.y, 0.f);
                v.z = fmaxf(v.z, 0.f); v.w = fmaxf(v.w, 0.f);
            }
            if (OSC) {
                const float d = dinv[r];
                v.x *= d; v.y *= d; v.z *= d; v.w *= d;
            }
            if (OUTH) {
                const __half2 h01 = __floats2half2_rn(v.x, v.y);
                const __half2 h23 = __floats2half2_rn(v.z, v.w);
                uint2 u;
                u.x = *(const unsigned int*)&h01;
                u.y = *(const unsigned int*)&h23;
                *(uint2*)((__half*)out + r * FO + 4 * colIdx) = u;
            } else {
                *(float4*)&out[r * FO + 4 * colIdx] = v;
            }
        }
    }
}

// ================= W prep: fp32 KxFO -> fp16 FOxK, k-permuted per 32-block (one-shot) ======
// pk = (k & ~31) + 8*((k>>2)&3) + 4*((k>>4)&1) + (k&3): lane frag = one contiguous half8.
template<int K, int FO>
__global__ __launch_bounds__(BLK) void wprep_k(const float* __restrict__ Wm, _Float16* __restrict__ Wh) {
    const int f = (blockIdx.x * BLK + threadIdx.x) * 4;
    if (f >= K * FO) return;
    const int nn = f / K, k0 = f % K;          // k0 % 4 == 0
    const int blk = k0 & ~31, g = (k0 >> 2) & 3, h = (k0 >> 4) & 1;
    half4v w4;
#pragma unroll
    for (int c = 0; c < 4; c++) w4[c] = (_Float16)Wm[(k0 + c) * FO + nn];
    *(half4v*)&Wh[nn * K + blk + 8 * g + 4 * h] = w4;
}

// ================= MFMA fp16 GEMM (big layers). BM=64: 4 waves x 16 rows. ==================
// B from pre-permuted Wh (coalesced copy). Frag layout v_mfma_f32_16x16x32_f16 (R5-verified):
//   A/B: row|col = lane&15, k = (lane>>4)*4 + (j&3) + 16*(j>>2);  C/D: col=lane&15, row=(lane>>4)*4+reg.
template<int K, int FO, bool AH, bool OUTB, bool OUTRELU, bool OSC, bool OUTH>
__global__ __launch_bounds__(BLK) void mgemm_k(const void* __restrict__ Hv, const _Float16* __restrict__ Wh,
                                               const float* __restrict__ bout, const float* __restrict__ dinv,
                                               void* __restrict__ outv, int n) {
    constexpr int BM = 64;             // rows per block (4 waves x 16 rows)
    constexpr int KP = K + 8;          // padded row stride (halves); KP*2 is 16B-multiple
    constexpr int NT = FO / 16;        // 16-col tiles
    __shared__ _Float16 Al[BM * KP];
    __shared__ _Float16 Bl[FO * KP];

    const int tid = threadIdx.x;
    const long rowBase = (long)blockIdx.x * BM;

    // ---- stage B: coalesced 16B copies of pre-permuted Wh ----
    for (int f = tid * 8; f < K * FO; f += BLK * 8) {
        const int nn = f / K, k = f % K;       // k % 8 == 0
        *(uint4*)&Bl[nn * KP + k] = *(const uint4*)&Wh[f];
    }
    // ---- stage A (permute on the fly) ----
    if (AH) {
        const __half* Hp = (const __half*)Hv;
        for (int f = tid * 8; f < BM * K; f += BLK * 8) {
            const int rr = f / K, k0 = f % K;  // k0 % 8 == 0
            const long r = rowBase + rr;
            uint4 u = make_uint4(0u, 0u, 0u, 0u);
            if (r < n) u = *(const uint4*)&Hp[r * K + k0];
            const int blk = k0 & ~31, g0 = (k0 >> 2) & 3, h = (k0 >> 4) & 1;
            *(uint2*)&Al[rr * KP + blk + 8 * g0 + 4 * h] = make_uint2(u.x, u.y);
            *(uint2*)&Al[rr * KP + blk + 8 * (g0 + 1) + 4 * h] = make_uint2(u.z, u.w);
        }
    } else {
        const float* Hp = (const float*)Hv;
        for (int f = tid * 4; f < BM * K; f += BLK * 4) {
            const int rr = f / K, k0 = f % K;  // k0 % 4 == 0
            const long r = rowBase + rr;
            float4 v = make_float4(0.f, 0.f, 0.f, 0.f);
            if (r < n) v = ld4(&Hp[r * K + k0]);
            const int blk = k0 & ~31, g = (k0 >> 2) & 3, h = (k0 >> 4) & 1;
            half4v a4;
            a4[0] = (_Float16)v.x; a4[1] = (_Float16)v.y; a4[2] = (_Float16)v.z; a4[3] = (_Float16)v.w;
            *(half4v*)&Al[rr * KP + blk + 8 * g + 4 * h] = a4;
        }
    }
    __syncthreads();

    // ---- MFMA main loop: wave wv owns rows [wv*16, wv*16+16) x all FO cols ----
    const int wv = tid >> 6;
    const int lane = tid & 63;
    const int lr = lane & 15;
    const int lg = lane >> 4;
    const int wrow = wv * 16;

    const f32x4v vzero = {0.f, 0.f, 0.f, 0.f};
    f32x4v acc[NT];
#pragma unroll
    for (int t = 0; t < NT; t++) acc[t] = vzero;

#pragma unroll
    for (int ks = 0; ks < K / 32; ks++) {
        const int ko = ks * 32 + 8 * lg;
        const half8v a = *(const half8v*)&Al[(wrow + lr) * KP + ko];
#pragma unroll
        for (int nt = 0; nt < NT; nt++) {
            const half8v b = *(const half8v*)&Bl[(nt * 16 + lr) * KP + ko];
            acc[nt] = __builtin_amdgcn_mfma_f32_16x16x32_f16(a, b, acc[nt], 0, 0, 0);
        }
    }

    // ---- epilogue ----
    float bo[NT];
    if (OUTB) {
#pragma unroll
        for (int nt = 0; nt < NT; nt++) bo[nt] = bout[nt * 16 + lr];
    }
#pragma unroll
    for (int r = 0; r < 4; r++) {
        const long row = rowBase + wrow + lg * 4 + r;
        if (row < n) {
            const float d = OSC ? dinv[row] : 1.0f;
#pragma unroll
            for (int nt = 0; nt < NT; nt++) {
                float v = acc[nt][r];
                if (OUTB) v += bo[nt];
                if (OUTRELU) v = fmaxf(v, 0.f);
                if (OSC) v *= d;
                if (OUTH) ((__half*)outv)[row * FO + nt * 16 + lr] = __float2half_rn(v);
                else      ((float*)outv)[row * FO + nt * 16 + lr] = v;
            }
        }
    }
}

extern "C" void kernel_launch(void* const* d_in, const int* in_sizes, int n_in,
                              void* d_out, int out_size, void* d_ws, size_t ws_size,
                              hipStream_t stream)
{
    const float* x  = (const float*)d_in[0];
    const int*   ei = (const int*)d_in[1];
    const float* W1 = (const float*)d_in[3];  const float* b1 = (const float*)d_in[4];
    const float* W2 = (const float*)d_in[5];  const float* b2 = (const float*)d_in[6];
    const float* W3 = (const float*)d_in[7];  const float* b3 = (const float*)d_in[8];
    const float* W4 = (const float*)d_in[9];  const float* b4 = (const float*)d_in[10];
    const float* W5 = (const float*)d_in[11]; const float* b5 = (const float*)d_in[12];
    const float* W6 = (const float*)d_in[13]; const float* b6 = (const float*)d_in[14];
    const float* Wf = (const float*)d_in[15]; const float* bf = (const float*)d_in[16];

    const int n = in_sizes[0] / 128;
    const int E = in_sizes[1] / 2;
    const int* rows = ei;       // source j
    const int* cols = ei + E;   // target i

    // workspace layout — total (n + E + n + 128n + 128n)*4 = 116,000,000 B (proven safe).
    int*   P    = (int*)d_ws;                        // n ints
    int*   srow = P + n;                             // E ints (16B-aligned for n%4==0)
    float* dinv = (float*)(srow + E);                // n floats
    float* bufA = dinv + n;                          // n*128 floats
    float* bufB = bufA + (size_t)n * 128;            // n*128 floats
    // pre-layer aliases (dead before first use of bufA/bufB by the layer pipeline):
    int*   pairs = (int*)bufA;                       // E packed ints = 12.8MB
    int*   hist  = (int*)bufB;                       // MAXNB*GPART ints = 1.64MB
    int*   bstart= hist + MAXNB * GPART;             // nb+1 ints (<= 1024+1)
    int*   tot   = bstart + 1032;                    // nb ints
    // persistent fp16 pre-permuted weights: bufB bytes [25.6MB, 25.6MB+64KB).
    // Every layer use of bufB is <= n*64 floats (= n*128 halves) = bytes [0, 25.6MB) -> no overlap.
    _Float16* Wh1 = (_Float16*)(bufB + (size_t)n * 64);  // 128*64
    _Float16* Wh6 = Wh1 + 128 * 64;                      // 64*128
    _Float16* Whf = Wh6 + 64 * 128;                      // 128*128

    auto cdiv = [](long a, long b) { return (unsigned)((a + b - 1) / b); };
    const int nb = (n + (1 << NBSHIFT) - 1) >> NBSHIFT;

    // --- one-shot W prep (touches only the Wh hole + weights) ---
    wprep_k<128, 64><<<cdiv(128 * 64 / 4, BLK), BLK, 0, stream>>>(W1, Wh1);
    wprep_k<64, 128><<<cdiv(64 * 128 / 4, BLK), BLK, 0, stream>>>(W6, Wh6);
    wprep_k<128, 128><<<cdiv(128 * 128 / 4, BLK), BLK, 0, stream>>>(Wf, Whf);

    // --- CSR build (atomic-free radix partition, 128-node buckets, packed 4B edges) ---
    p1_hist_k<<<GPART, BLK, 0, stream>>>(cols, hist, E, nb);
    p2a_tot_k<<<nb, 256, 0, stream>>>(hist, tot);
    p2a_scan_k<<<1, 256, 0, stream>>>(tot, bstart, nb, E);
    p2b_k<<<nb, 256, 0, stream>>>(hist, bstart);
    p3_part_k<<<GPART, BLK, 0, stream>>>(rows, cols, hist, pairs, E, nb);
    p4_fill_k<<<nb, BLK, 0, stream>>>(pairs, bstart, P, dinv, srow, n);

    // --- layers (ALL intermediates fp16; fp32 accumulation everywhere) ---
    // L1 (MFMA): t1' = (x@W1)*dinv [fp16] ; a1 = gather_h(t1') -> fp16  [deferred: +b1, relu]
    mgemm_k<128, 64, false, false, false, true, true><<<cdiv(n, 64), BLK, 0, stream>>>(x, Wh1, nullptr, dinv, bufA, n);
    gatherh_k<64, false, true><<<cdiv((long)n * 8, BLK), BLK, 0, stream>>>((const __half*)bufA, P, srow, dinv, nullptr, bufB, n, E);

    // L2: t2' = (relu(a1+b1)@W2)*dinv [fp16] ; a2 = gather_h -> fp16    [deferred: +b2, relu]
    gemm_k<64, 32, true, false, false, true, true, true><<<cdiv(n, 128), BLK, 0, stream>>>(bufB, W2, b1, nullptr, dinv, bufA, n);
    gatherh_k<32, false, true><<<cdiv((long)n * 4, BLK), BLK, 0, stream>>>((const __half*)bufA, P, srow, dinv, nullptr, bufB, n, E);

    // L3: t3' = (relu(a2+b2)@W3)*dinv [fp16] ; gather w/ fused epilogue -> t4' = relu(a3+b3)*dinv [fp16]
    gemm_k<32, 16, true, false, false, true, true, true><<<cdiv(n, 256), BLK, 0, stream>>>(bufB, W3, b2, nullptr, dinv, bufA, n);
    gatherh_k<16, true, true><<<cdiv((long)n * 2, BLK), BLK, 0, stream>>>((const __half*)bufA, P, srow, dinv, b3, bufB, n, E);

    // L4: a4 = gather_h(t4') -> fp16 ; h4' = relu(a4@W4+b4)*dinv [fp16]
    gatherh_k<16, false, true><<<cdiv((long)n * 2, BLK), BLK, 0, stream>>>((const __half*)bufB, P, srow, dinv, nullptr, bufA, n, E);
    gemm_k<16, 32, false, true, true, true, true, true><<<cdiv(n, 128), BLK, 0, stream>>>(bufA, W4, nullptr, b4, dinv, bufB, n);

    // L5: a5 = gather_h(h4') -> fp16 ; h5' = relu(a5@W5+b5)*dinv [fp16]
    gatherh_k<32, false, true><<<cdiv((long)n * 4, BLK), BLK, 0, stream>>>((const __half*)bufB, P, srow, dinv, nullptr, bufA, n, E);
    gemm_k<32, 64, false, true, true, true, true, true><<<cdiv(n, 128), BLK, 0, stream>>>(bufA, W5, nullptr, b5, dinv, bufB, n);

    // L6: a6 = gather_h(h5') -> fp16 ; (MFMA) h6 = relu(a6@W6+b6) [fp16]
    gatherh_k<64, false, true><<<cdiv((long)n * 8, BLK), BLK, 0, stream>>>((const __half*)bufB, P, srow, dinv, nullptr, bufA, n, E);
    mgemm_k<64, 128, true, true, true, false, true><<<cdiv(n, 64), BLK, 0, stream>>>(bufA, Wh6, b6, nullptr, bufB, n);

    // final (MFMA): out = h6 @ Wf + bf  [fp32 out]
    mgemm_k<128, 128, true, true, false, false, false><<<cdiv(n, 64), BLK, 0, stream>>>(bufB, Whf, bf, nullptr, d_out, n);
}